// Round 8
// baseline (2243.422 us; speedup 1.0000x reference)
//
#include <hip/hip_runtime.h>
#include <hip/hip_bf16.h>
#include <math.h>

// Problem constants
#define B_SZ 1024
#define T_SZ 512
#define CTX_N 23
#define D 320
#define L_LAYERS 5
#define H 8
#define FF 1280
#define NM1 49      // NMODES + 1
#define S 24        // CTX + 1
#define DH 40       // D / H
#define M_ROWS (B_SZ * S)   // 24576

typedef unsigned short ushort_t;
typedef __attribute__((ext_vector_type(8))) short bfrag8;   // 8 bf16 (4 VGPRs)
typedef __attribute__((ext_vector_type(4))) float facc4;    // 4 fp32 acc

__device__ __forceinline__ float wave_sum(float v) {
#pragma unroll
  for (int off = 32; off > 0; off >>= 1) v += __shfl_xor(v, off, 64);
  return v;
}

// tanh-form gelu (max |err| ~3e-4 << bf16 quantum, safe at +-inf)
__device__ __forceinline__ float gelu_fast(float x) {
  float t = __builtin_amdgcn_exp2f(x * (2.30211416f + 0.10294404f * x * x));
  return x - x * __builtin_amdgcn_rcpf(t + 1.0f);
}

__device__ __forceinline__ ushort_t f2b(float x) {
  __hip_bfloat16 h = __float2bfloat16(x);
  return *reinterpret_cast<ushort_t*>(&h);
}

__device__ __forceinline__ float b2f(ushort_t u) {
  __hip_bfloat16 h = *reinterpret_cast<__hip_bfloat16*>(&u);
  return __bfloat162float(h);
}

// ---------------- all-weights f32 -> bf16 (dst regions contiguous) -----------
__global__ __launch_bounds__(256) void conv_all(
    const float* __restrict__ w_in, const float* __restrict__ w_out,
    const float* __restrict__ w1, const float* __restrict__ w2,
    const float* __restrict__ wh1, ushort_t* __restrict__ dst) {
  int i = blockIdx.x * 256 + threadIdx.x;
  const float* src;
  int off;
  if (i < 384000)       { src = w_in;  off = i; }
  else if (i < 512000)  { src = w_out; off = i - 384000; }
  else if (i < 1024000) { src = w1;    off = i - 512000; }
  else if (i < 1536000) { src = w2;    off = i - 1024000; }
  else                  { src = wh1;   off = i - 1536000; }
  float4 v = ((const float4*)src)[off];
  ushort4 o;
  o.x = f2b(v.x); o.y = f2b(v.y); o.z = f2b(v.z); o.w = f2b(v.w);
  ((ushort4*)dst)[i] = o;
}

// ---------------- embed + LN1(layer0) fused: one wave per row ----------------
// Writes x (residual stream, f32) AND hbuf = ln1_0(x) (bf16) in one pass.
__global__ __launch_bounds__(256) void embed_ln(
    const float* __restrict__ ctx, const float* __restrict__ W_e,
    const float* __restrict__ b_e, const float* __restrict__ cls,
    const float* __restrict__ lnw, const float* __restrict__ lnb,
    float* __restrict__ x, ushort_t* __restrict__ y) {
  int wv = threadIdx.x >> 6;
  int lane = threadIdx.x & 63;
  int row = blockIdx.x * 4 + wv;   // row = b*S + s
  int s = row % S;
  int b = row / S;
  float cv = (s == 0) ? 0.f : ctx[b * CTX_N + (s - 1)];
  float v[5];
#pragma unroll
  for (int i = 0; i < 5; i++) {
    int d = lane + 64 * i;
    v[i] = (s == 0) ? cls[d] : cv * W_e[d] + b_e[d];
  }
  float* xr = x + (size_t)row * D;
#pragma unroll
  for (int i = 0; i < 5; i++) xr[lane + 64 * i] = v[i];
  float sm = v[0] + v[1] + v[2] + v[3] + v[4];
  sm = wave_sum(sm);
  float m = sm * (1.0f / (float)D);
  float sq = 0.f;
#pragma unroll
  for (int i = 0; i < 5; i++) { float d0 = v[i] - m; sq += d0 * d0; }
  sq = wave_sum(sq);
  float inv = 1.0f / sqrtf(sq * (1.0f / (float)D) + 1e-5f);
  ushort_t* yr = y + (size_t)row * D;
#pragma unroll
  for (int i = 0; i < 5; i++) {
    int d = lane + 64 * i;
    yr[d] = f2b((v[i] - m) * inv * lnw[d] + lnb[d]);
  }
}

// ---------------- layernorm: fp32 in, bf16 out, one wave per row -------------
// (still used for the head LN on CLS rows)
__global__ __launch_bounds__(256) void ln_kernel(
    const float* __restrict__ X, const float* __restrict__ w,
    const float* __restrict__ b, ushort_t* __restrict__ Y,
    int inStride, int outStride) {
  int wv = threadIdx.x >> 6;
  int lane = threadIdx.x & 63;
  int row = blockIdx.x * 4 + wv;
  const float* xr = X + (size_t)row * inStride;
  float v[5];
#pragma unroll
  for (int i = 0; i < 5; i++) v[i] = xr[lane + 64 * i];
  float s = v[0] + v[1] + v[2] + v[3] + v[4];
  s = wave_sum(s);
  float m = s * (1.0f / (float)D);
  float sq = 0.f;
#pragma unroll
  for (int i = 0; i < 5; i++) { float d0 = v[i] - m; sq += d0 * d0; }
  sq = wave_sum(sq);
  float inv = 1.0f / sqrtf(sq * (1.0f / (float)D) + 1e-5f);
  ushort_t* yr = Y + (size_t)row * outStride;
#pragma unroll
  for (int i = 0; i < 5; i++) {
    int d = lane + 64 * i;
    yr[d] = f2b((v[i] - m) * inv * w[d] + b[d]);
  }
}

// ---------------- bf16 MFMA GEMM, T14 reg-staged (R8) ------------------------
// BM=MT*32, BK=64, BN=32*NT. 256 threads = 4 waves (2x2). Single LDS buffer,
// 2 __syncthreads/step (R0-proven sync structure; NO raw barriers).
// R8 change: staging goes global->VGPR->ds_write instead of global_load_lds.
// Evidence: R6/R7 A/B showed occupancy 13->22% with ZERO duration change on
// the fat GEMMs (54.5 vs 55.8us) -> not TLP-bound; every gload_lds variant
// pinned at 45-56us, ~1.8TB/s, MfmaUtil 13-16%, conflicts 0 -> suspected
// limiter is the global_load_lds staging path itself. T14 split: issue tile
// t+1's loads BEFORE computing tile t (HBM latency hides under compute);
// ds_write happens after the barrier (compiler inserts the vmcnt wait there).
// Per step: sync; ds_write(t); sync; issue(t+1); ds_read+MFMA(t).
// Swizzled K-contiguous layout (chunk j of row r at slot j^(r&7)):
// conflict-free (measured 0). Swapped MFMA operands -> D[n][m].
// T1 XCD remap kept (nbx % 8 == 0 for all grids; bijective).
// EPI: 1=bias+gelu->bf16, 2=bias+residual->f32, 3=bias+gelu->f32,
//      4=bias->bf16, 5=bias+residual->f32 x AND fused row-LN->bf16 Cb
//      (EPI=5 requires BN == N; NT=10, MT=2; launch_bounds min-waves 2
//      because 12 staging uint4 + 80 acc VGPRs exceed the 3-wave budget).
template <int EPI, int NT, int MT>
__global__ __launch_bounds__(256, (EPI == 5) ? 2 : 3) void gemm_mfma(
    const ushort_t* __restrict__ A, const ushort_t* __restrict__ W,
    const float* __restrict__ bias, const float* __restrict__ R,
    float* __restrict__ C, ushort_t* __restrict__ Cb,
    const float* __restrict__ lnw, const float* __restrict__ lnb,
    int M, int N, int K) {
  constexpr int BM_ = MT * 32, BK = 64;
  constexpr int BN = 32 * NT;
  constexpr int AR = BM_ / 32;   // A staging rounds (32 rows each)
  constexpr int WR = BN / 32;    // W staging rounds
  __shared__ __align__(16) ushort_t As[BM_ * BK];
  __shared__ __align__(16) ushort_t Ws[BN * BK];
  __shared__ float psum[2][(EPI == 5) ? BM_ : 4];  // fused-LN partials
  __shared__ float psq[2][(EPI == 5) ? BM_ : 4];

  int tid = threadIdx.x;
  int lane = tid & 63;
  int wv = tid >> 6;
  int wvM = wv & 1, wvN = wv >> 1;
  int laneM = lane & 15;
  int kgrp = lane >> 4;
  int sA = laneM & 7;

  // T1 XCD-aware remap (requires nbx % 8 == 0; bijective)
  int nbx = gridDim.x;
  int lid = blockIdx.x + nbx * blockIdx.y;
  int nchunk = nbx >> 3;
  int mb = (lid & 7) * nchunk + ((lid >> 3) % nchunk);
  int nb = (lid >> 3) / nchunk;
  int m0 = mb * BM_;
  int n0 = nb * BN;

  facc4 acc[MT][NT];
#pragma unroll
  for (int mt = 0; mt < MT; mt++)
#pragma unroll
    for (int nt = 0; nt < NT; nt++) acc[mt][nt] = (facc4){0.f, 0.f, 0.f, 0.f};

  int srow = tid >> 3;
  int jg = (tid & 7) ^ (srow & 7);
  const ushort_t* Ag = A + (size_t)(m0 + srow) * K + jg * 8;
  const ushort_t* Wg = W + (size_t)(n0 + srow) * K + jg * 8;

  uint4 rA[AR], rW[WR];   // in-flight staging registers (T14)
  auto issue = [&](int k0) {
#pragma unroll
    for (int r = 0; r < AR; r++)
      rA[r] = *(const uint4*)(Ag + (size_t)r * 32 * K + k0);
#pragma unroll
    for (int r = 0; r < WR; r++)
      rW[r] = *(const uint4*)(Wg + (size_t)r * 32 * K + k0);
  };
  auto write_lds = [&]() {
#pragma unroll
    for (int r = 0; r < AR; r++)
      *(uint4*)(As + r * 2048 + tid * 8) = rA[r];
#pragma unroll
    for (int r = 0; r < WR; r++)
      *(uint4*)(Ws + r * 2048 + tid * 8) = rW[r];
  };

  issue(0);   // prologue: tile 0 loads in flight
  for (int k0 = 0; k0 < K; k0 += BK) {
    __syncthreads();   // all waves done reading the previous tile
    write_lds();       // vmcnt wait inserted here by compiler
    __syncthreads();   // tile k0 visible to all waves
    if (k0 + BK < K) issue(k0 + BK);  // prefetch t+1 under t's compute
#pragma unroll
    for (int kc = 0; kc < 2; kc++) {
      int jcol = ((kc * 4 + kgrp) ^ sA) * 8;
      bfrag8 af[MT];
#pragma unroll
      for (int mt = 0; mt < MT; mt++) {
        int row = wvM * (MT * 16) + mt * 16 + laneM;
        af[mt] = *(const bfrag8*)&As[row * 64 + jcol];
      }
#pragma unroll
      for (int nt = 0; nt < NT; nt++) {
        int nrow = wvN * (BN / 2) + nt * 16 + laneM;
        bfrag8 bf = *(const bfrag8*)&Ws[nrow * 64 + jcol];
#pragma unroll
        for (int mt = 0; mt < MT; mt++)
          acc[mt][nt] = __builtin_amdgcn_mfma_f32_16x16x32_bf16(
              bf, af[mt], acc[mt][nt], 0, 0, 0);   // swapped: D[n][m]
      }
    }
  }

  if constexpr (EPI == 5) {
    // ---- fused epilogue: v = acc + bias + residual; x=v; Cb=LN(v) ----
    float rs[MT], rq[MT];
#pragma unroll
    for (int mt = 0; mt < MT; mt++) { rs[mt] = 0.f; rq[mt] = 0.f; }
#pragma unroll
    for (int mt = 0; mt < MT; mt++) {
      int m = m0 + wvM * (MT * 16) + mt * 16 + laneM;
#pragma unroll
      for (int nt = 0; nt < NT; nt++) {
        int n = n0 + wvN * (BN / 2) + nt * 16 + kgrp * 4;
        float4 bv = *(const float4*)(bias + n);
        size_t off = (size_t)m * N + n;
        float4 r = *(const float4*)(R + off);
        facc4 a = acc[mt][nt];
        a[0] += bv.x + r.x; a[1] += bv.y + r.y;
        a[2] += bv.z + r.z; a[3] += bv.w + r.w;
        acc[mt][nt] = a;
        rs[mt] += a[0] + a[1] + a[2] + a[3];
        rq[mt] += a[0] * a[0] + a[1] * a[1] + a[2] * a[2] + a[3] * a[3];
      }
    }
    // reduce across the 4 kgrp lanes holding the same row (lanes ^16, ^32)
#pragma unroll
    for (int mt = 0; mt < MT; mt++) {
      rs[mt] += __shfl_xor(rs[mt], 16, 64);
      rs[mt] += __shfl_xor(rs[mt], 32, 64);
      rq[mt] += __shfl_xor(rq[mt], 16, 64);
      rq[mt] += __shfl_xor(rq[mt], 32, 64);
    }
    __syncthreads();   // LDS reads of the K-loop done before psum reuse
    if (lane < 16) {   // kgrp == 0 lanes publish per-wvN row partials
#pragma unroll
      for (int mt = 0; mt < MT; mt++) {
        int lr = wvM * (MT * 16) + mt * 16 + laneM;
        psum[wvN][lr] = rs[mt];
        psq[wvN][lr] = rq[mt];
      }
    }
    __syncthreads();
#pragma unroll
    for (int mt = 0; mt < MT; mt++) {
      int lr = wvM * (MT * 16) + mt * 16 + laneM;
      int m = m0 + lr;
      float ts = psum[0][lr] + psum[1][lr];
      float tq = psq[0][lr] + psq[1][lr];
      float mean = ts * (1.0f / (float)D);
      float var = tq * (1.0f / (float)D) - mean * mean;
      float inv = 1.0f / sqrtf(var + 1e-5f);
#pragma unroll
      for (int nt = 0; nt < NT; nt++) {
        int n = n0 + wvN * (BN / 2) + nt * 16 + kgrp * 4;
        size_t off = (size_t)m * N + n;
        facc4 a = acc[mt][nt];
        *(float4*)(C + off) = (float4){a[0], a[1], a[2], a[3]};
        float4 w4 = *(const float4*)(lnw + n);
        float4 b4 = *(const float4*)(lnb + n);
        ushort4 o;
        o.x = f2b((a[0] - mean) * inv * w4.x + b4.x);
        o.y = f2b((a[1] - mean) * inv * w4.y + b4.y);
        o.z = f2b((a[2] - mean) * inv * w4.z + b4.z);
        o.w = f2b((a[3] - mean) * inv * w4.w + b4.w);
        *(ushort4*)(Cb + off) = o;
      }
    }
  } else {
    // epilogue (transposed D): m = laneM-based, n = kgrp*4 + reg
#pragma unroll
    for (int mt = 0; mt < MT; mt++) {
      int m = m0 + wvM * (MT * 16) + mt * 16 + laneM;
#pragma unroll
      for (int nt = 0; nt < NT; nt++) {
        int n = n0 + wvN * (BN / 2) + nt * 16 + kgrp * 4;
        float4 bv = *(const float4*)(bias + n);
        facc4 a = acc[mt][nt];
        float v0 = a[0] + bv.x, v1 = a[1] + bv.y, v2 = a[2] + bv.z,
              v3 = a[3] + bv.w;
        size_t off = (size_t)m * N + n;
        if constexpr (EPI == 1) {
          ushort4 o;
          o.x = f2b(gelu_fast(v0)); o.y = f2b(gelu_fast(v1));
          o.z = f2b(gelu_fast(v2)); o.w = f2b(gelu_fast(v3));
          *(ushort4*)(Cb + off) = o;
        } else if constexpr (EPI == 2) {
          float4 r = *(const float4*)(R + off);
          float4 o = {v0 + r.x, v1 + r.y, v2 + r.z, v3 + r.w};
          *(float4*)(C + off) = o;
        } else if constexpr (EPI == 3) {
          float4 o = {gelu_fast(v0), gelu_fast(v1), gelu_fast(v2),
                      gelu_fast(v3)};
          *(float4*)(C + off) = o;
        } else {  // EPI == 4
          ushort4 o;
          o.x = f2b(v0); o.y = f2b(v1); o.z = f2b(v2); o.w = f2b(v3);
          *(ushort4*)(Cb + off) = o;
        }
      }
    }
  }
}

// ---------------- attention v2: one block per (b,h), conflict-free LDS -------
__global__ __launch_bounds__(256) void attn_kernel(
    const ushort_t* __restrict__ qkv, ushort_t* __restrict__ o) {
  int b = blockIdx.x >> 3;
  int h = blockIdx.x & 7;
  __shared__ __align__(16) float q[S][44];
  __shared__ __align__(16) float v[S][44];
  __shared__ __align__(16) float kT[DH][28];
  __shared__ __align__(16) float sc[S][28];
  int tid = threadIdx.x;
  const ushort_t* base = qkv + (size_t)b * S * (3 * D) + h * DH;

  for (int idx = tid; idx < 720; idx += 256) {
    int t = idx / 240;          // 0=q 1=k 2=v
    int r = idx % 240;
    int s = r / 10, dg = r % 10;
    ushort4 u = *(const ushort4*)(base + (size_t)s * (3 * D) + t * D + dg * 4);
    float4 f = {b2f(u.x), b2f(u.y), b2f(u.z), b2f(u.w)};
    if (t == 0) {
      *(float4*)&q[s][dg * 4] = f;
    } else if (t == 2) {
      *(float4*)&v[s][dg * 4] = f;
    } else {
      kT[dg * 4 + 0][s] = f.x;
      kT[dg * 4 + 1][s] = f.y;
      kT[dg * 4 + 2][s] = f.z;
      kT[dg * 4 + 3][s] = f.w;
    }
  }
  __syncthreads();

  if (tid < 144) {
    int i = tid / 6, jg = tid % 6;
    facc4 acc = {0.f, 0.f, 0.f, 0.f};
#pragma unroll
    for (int d = 0; d < DH; d++) {
      float qv = q[i][d];
      float4 kv = *(const float4*)&kT[d][jg * 4];
      acc[0] += qv * kv.x; acc[1] += qv * kv.y;
      acc[2] += qv * kv.z; acc[3] += qv * kv.w;
    }
    const float sca = 0.15811388300841897f;  // 1/sqrt(40)
    float4 ov = {acc[0] * sca, acc[1] * sca, acc[2] * sca, acc[3] * sca};
    *(float4*)&sc[i][jg * 4] = ov;
  }
  __syncthreads();

  if (tid < S) {
    float mx = -1e30f;
#pragma unroll
    for (int j = 0; j < S; j++) mx = fmaxf(mx, sc[tid][j]);
    float sum = 0.f;
#pragma unroll
    for (int j = 0; j < S; j++) {
      float e = __expf(sc[tid][j] - mx);
      sc[tid][j] = e;
      sum += e;
    }
    float rr = 1.0f / sum;
#pragma unroll
    for (int j = 0; j < S; j++) sc[tid][j] *= rr;
  }
  __syncthreads();

  if (tid < 240) {
    int i = tid / 10, dg = tid % 10;
    facc4 acc = {0.f, 0.f, 0.f, 0.f};
#pragma unroll
    for (int j = 0; j < S; j++) {
      float p = sc[i][j];
      float4 vv = *(const float4*)&v[j][dg * 4];
      acc[0] += p * vv.x; acc[1] += p * vv.y;
      acc[2] += p * vv.z; acc[3] += p * vv.w;
    }
    ushort4 ov;
    ov.x = f2b(acc[0]); ov.y = f2b(acc[1]);
    ov.z = f2b(acc[2]); ov.w = f2b(acc[3]);
    *(ushort4*)(o + (size_t)b * S * D + (size_t)i * D + h * DH + dg * 4) = ov;
  }
}

// ---------------- head tail: c = g@Wh2^T+bh2 ; cheb ; sigmoid ----------------
__global__ __launch_bounds__(256) void head_cheb(
    const float* __restrict__ g, const float* __restrict__ Wh2,
    const float* __restrict__ bh2, const float* __restrict__ k_norm,
    float* __restrict__ out) {
  int b = blockIdx.x;
  __shared__ float gs[D];
  __shared__ float cs[NM1];
  int tid = threadIdx.x;
  for (int i = tid; i < D; i += 256) gs[i] = g[(size_t)b * D + i];
  __syncthreads();
  if (tid < NM1) {
    const float* wr = Wh2 + (size_t)tid * D;
    float s = bh2[tid];
    for (int d = 0; d < D; d++) s += gs[d] * wr[d];
    cs[tid] = s;
  }
  __syncthreads();
  for (int t = tid; t < T_SZ; t += 256) {
    float xv = k_norm[(size_t)b * T_SZ + t];
    float tp = 1.f, tc = xv;
    float acc = cs[0] + cs[1] * xv;
#pragma unroll
    for (int n = 2; n < NM1; n++) {
      float tn = 2.f * xv * tc - tp;
      acc += cs[n] * tn;
      tp = tc;
      tc = tn;
    }
    out[(size_t)b * T_SZ + t] = 1.f / (1.f + expf(-acc));
  }
}

extern "C" void kernel_launch(void* const* d_in, const int* in_sizes, int n_in,
                              void* d_out, int out_size, void* d_ws,
                              size_t ws_size, hipStream_t stream) {
  const float* k_norm = (const float*)d_in[0];
  const float* ctx    = (const float*)d_in[1];
  const float* W_e    = (const float*)d_in[2];
  const float* b_e    = (const float*)d_in[3];
  const float* cls    = (const float*)d_in[4];
  const float* ln1_w  = (const float*)d_in[5];
  const float* ln1_b  = (const float*)d_in[6];
  const float* W_in   = (const float*)d_in[7];
  const float* b_in   = (const float*)d_in[8];
  const float* W_out  = (const float*)d_in[9];
  const float* b_out  = (const float*)d_in[10];
  const float* ln2_w  = (const float*)d_in[11];
  const float* ln2_b  = (const float*)d_in[12];
  const float* W1     = (const float*)d_in[13];
  const float* b1     = (const float*)d_in[14];
  const float* W2     = (const float*)d_in[15];
  const float* b2     = (const float*)d_in[16];
  const float* hln_w  = (const float*)d_in[17];
  const float* hln_b  = (const float*)d_in[18];
  const float* Wh1    = (const float*)d_in[19];
  const float* bh1    = (const float*)d_in[20];
  const float* Wh2    = (const float*)d_in[21];
  const float* bh2    = (const float*)d_in[22];
  float* out = (float*)d_out;

  float* x = (float*)d_ws;
  ushort_t* hbuf = (ushort_t*)(x + (size_t)M_ROWS * D);
  ushort_t* big = hbuf + (size_t)M_ROWS * D;
  ushort_t* wb_in = big + (size_t)M_ROWS * FF;
  ushort_t* wb_out = wb_in + (size_t)L_LAYERS * 3 * D * D;
  ushort_t* wb1 = wb_out + (size_t)L_LAYERS * D * D;
  ushort_t* wb2 = wb1 + (size_t)L_LAYERS * FF * D;
  ushort_t* wbh1 = wb2 + (size_t)L_LAYERS * D * FF;
  ushort_t* hcls = wbh1 + (size_t)D * D;
  float* ghead = (float*)(hcls + (size_t)B_SZ * D);
  // attn output lives in the tail of big (cols 960..1280 region, disjoint
  // from the qkv output in cols 0..960; both dead once ffn1 overwrites big)
  ushort_t* abuf = big + (size_t)M_ROWS * 960;

  conv_all<<<6100, 256, 0, stream>>>(W_in, W_out, W1, W2, Wh1, wb_in);

  // embed + ln1(layer 0): writes x (f32) and hbuf = ln1_0(x) (bf16)
  embed_ln<<<M_ROWS / 4, 256, 0, stream>>>(ctx, W_e, b_e, cls, ln1_w, ln1_b,
                                           x, hbuf);

  for (int l = 0; l < L_LAYERS; l++) {
    gemm_mfma<4, 5, 4><<<dim3(M_ROWS / 128, (3 * D) / 160), 256, 0, stream>>>(
        hbuf, wb_in + (size_t)l * 3 * D * D, b_in + (size_t)l * 3 * D, nullptr,
        nullptr, big, nullptr, nullptr, M_ROWS, 3 * D, D);
    attn_kernel<<<B_SZ * H, 256, 0, stream>>>(big, abuf);
    // proj + residual + fused ln2 -> x (f32) and hbuf (bf16); MT=2 (R6-best)
    gemm_mfma<5, 10, 2><<<dim3(M_ROWS / 64, 1), 256, 0, stream>>>(
        abuf, wb_out + (size_t)l * D * D, b_out + (size_t)l * D, x, x, hbuf,
        ln2_w + (size_t)l * D, ln2_b + (size_t)l * D, M_ROWS, D, D);
    gemm_mfma<1, 5, 4><<<dim3(M_ROWS / 128, FF / 160), 256, 0, stream>>>(
        hbuf, wb1 + (size_t)l * FF * D, b1 + (size_t)l * FF, nullptr, nullptr,
        big, nullptr, nullptr, M_ROWS, FF, D);
    if (l + 1 < L_LAYERS) {
      // ffn2 + residual + fused ln1(l+1) -> x (f32) and hbuf (bf16)
      gemm_mfma<5, 10, 2><<<dim3(M_ROWS / 64, 1), 256, 0, stream>>>(
          big, wb2 + (size_t)l * D * FF, b2 + (size_t)l * D, x, x, hbuf,
          ln1_w + (size_t)(l + 1) * D, ln1_b + (size_t)(l + 1) * D,
          M_ROWS, D, FF);
    } else {
      gemm_mfma<2, 5, 2><<<dim3(M_ROWS / 64, D / 160), 256, 0, stream>>>(
          big, wb2 + (size_t)l * D * FF, b2 + (size_t)l * D, x, x, nullptr,
          nullptr, nullptr, M_ROWS, D, FF);
    }
  }

  ln_kernel<<<B_SZ / 4, 256, 0, stream>>>(x, hln_w, hln_b, hcls, S * D, D);
  gemm_mfma<3, 5, 2><<<dim3(B_SZ / 64, D / 160), 256, 0, stream>>>(
      hcls, wbh1, bh1, nullptr, ghead, nullptr, nullptr, nullptr, B_SZ, D, D);
  head_cheb<<<B_SZ, 256, 0, stream>>>(ghead, Wh2, bh2, k_norm, out);
}

// Round 9
// 1028.906 us; speedup vs baseline: 2.1804x; 2.1804x over previous
//
#include <hip/hip_runtime.h>
#include <hip/hip_bf16.h>
#include <math.h>

// Problem constants
#define B_SZ 1024
#define T_SZ 512
#define CTX_N 23
#define D 320
#define L_LAYERS 5
#define H 8
#define FF 1280
#define NM1 49      // NMODES + 1
#define S 24        // CTX + 1
#define DH 40       // D / H
#define M_ROWS (B_SZ * S)   // 24576

typedef unsigned short ushort_t;
typedef __attribute__((ext_vector_type(8))) short bfrag8;   // 8 bf16 (4 VGPRs)
typedef __attribute__((ext_vector_type(4))) float facc4;    // 4 fp32 acc

__device__ __forceinline__ float wave_sum(float v) {
#pragma unroll
  for (int off = 32; off > 0; off >>= 1) v += __shfl_xor(v, off, 64);
  return v;
}

// tanh-form gelu (max |err| ~3e-4 << bf16 quantum, safe at +-inf)
__device__ __forceinline__ float gelu_fast(float x) {
  float t = __builtin_amdgcn_exp2f(x * (2.30211416f + 0.10294404f * x * x));
  return x - x * __builtin_amdgcn_rcpf(t + 1.0f);
}

__device__ __forceinline__ ushort_t f2b(float x) {
  __hip_bfloat16 h = __float2bfloat16(x);
  return *reinterpret_cast<ushort_t*>(&h);
}

__device__ __forceinline__ float b2f(ushort_t u) {
  __hip_bfloat16 h = *reinterpret_cast<__hip_bfloat16*>(&u);
  return __bfloat162float(h);
}

#define GLOAD_LDS16(g, l)                                     \
  __builtin_amdgcn_global_load_lds(                           \
      (const __attribute__((address_space(1))) void*)(g),     \
      (__attribute__((address_space(3))) void*)(l), 16, 0, 0)

// ---------------- all-weights f32 -> bf16 (dst regions contiguous) -----------
__global__ __launch_bounds__(256) void conv_all(
    const float* __restrict__ w_in, const float* __restrict__ w_out,
    const float* __restrict__ w1, const float* __restrict__ w2,
    const float* __restrict__ wh1, ushort_t* __restrict__ dst) {
  int i = blockIdx.x * 256 + threadIdx.x;
  const float* src;
  int off;
  if (i < 384000)       { src = w_in;  off = i; }
  else if (i < 512000)  { src = w_out; off = i - 384000; }
  else if (i < 1024000) { src = w1;    off = i - 512000; }
  else if (i < 1536000) { src = w2;    off = i - 1024000; }
  else                  { src = wh1;   off = i - 1536000; }
  float4 v = ((const float4*)src)[off];
  ushort4 o;
  o.x = f2b(v.x); o.y = f2b(v.y); o.z = f2b(v.z); o.w = f2b(v.w);
  ((ushort4*)dst)[i] = o;
}

// ---------------- embed + LN1(layer0) fused: one wave per row ----------------
// Writes x (residual stream, f32) AND hbuf = ln1_0(x) (bf16) in one pass.
__global__ __launch_bounds__(256) void embed_ln(
    const float* __restrict__ ctx, const float* __restrict__ W_e,
    const float* __restrict__ b_e, const float* __restrict__ cls,
    const float* __restrict__ lnw, const float* __restrict__ lnb,
    float* __restrict__ x, ushort_t* __restrict__ y) {
  int wv = threadIdx.x >> 6;
  int lane = threadIdx.x & 63;
  int row = blockIdx.x * 4 + wv;   // row = b*S + s
  int s = row % S;
  int b = row / S;
  float cv = (s == 0) ? 0.f : ctx[b * CTX_N + (s - 1)];
  float v[5];
#pragma unroll
  for (int i = 0; i < 5; i++) {
    int d = lane + 64 * i;
    v[i] = (s == 0) ? cls[d] : cv * W_e[d] + b_e[d];
  }
  float* xr = x + (size_t)row * D;
#pragma unroll
  for (int i = 0; i < 5; i++) xr[lane + 64 * i] = v[i];
  float sm = v[0] + v[1] + v[2] + v[3] + v[4];
  sm = wave_sum(sm);
  float m = sm * (1.0f / (float)D);
  float sq = 0.f;
#pragma unroll
  for (int i = 0; i < 5; i++) { float d0 = v[i] - m; sq += d0 * d0; }
  sq = wave_sum(sq);
  float inv = 1.0f / sqrtf(sq * (1.0f / (float)D) + 1e-5f);
  ushort_t* yr = y + (size_t)row * D;
#pragma unroll
  for (int i = 0; i < 5; i++) {
    int d = lane + 64 * i;
    yr[d] = f2b((v[i] - m) * inv * lnw[d] + lnb[d]);
  }
}

// ---------------- layernorm: fp32 in, bf16 out, one wave per row -------------
__global__ __launch_bounds__(256) void ln_kernel(
    const float* __restrict__ X, const float* __restrict__ w,
    const float* __restrict__ b, ushort_t* __restrict__ Y,
    int inStride, int outStride) {
  int wv = threadIdx.x >> 6;
  int lane = threadIdx.x & 63;
  int row = blockIdx.x * 4 + wv;
  const float* xr = X + (size_t)row * inStride;
  float v[5];
#pragma unroll
  for (int i = 0; i < 5; i++) v[i] = xr[lane + 64 * i];
  float s = v[0] + v[1] + v[2] + v[3] + v[4];
  s = wave_sum(s);
  float m = s * (1.0f / (float)D);
  float sq = 0.f;
#pragma unroll
  for (int i = 0; i < 5; i++) { float d0 = v[i] - m; sq += d0 * d0; }
  sq = wave_sum(sq);
  float inv = 1.0f / sqrtf(sq * (1.0f / (float)D) + 1e-5f);
  ushort_t* yr = Y + (size_t)row * outStride;
#pragma unroll
  for (int i = 0; i < 5; i++) {
    int d = lane + 64 * i;
    yr[d] = f2b((v[i] - m) * inv * w[d] + b[d]);
  }
}

// ---------------- bf16 MFMA GEMM (R6 form: gload_lds, single buffer) ---------
// BM=MT*32, BK=64, BN=32*NT. 256 threads = 4 waves (2x2). Single LDS buffer,
// 2 __syncthreads/step. Swizzled K-contiguous layout (chunk j of row r at
// slot j^(r&7)): conflict-free (measured 0). Swapped MFMA -> D[n][m].
// T1 XCD remap (nbx % 8 == 0; bijective).
// Session ledger: MT/tile shape (R1), XCD swizzle (R2), drain-0 dbuf (R3),
// raw-barrier counted-vmcnt (R4/R5: container hangs), occupancy via MT=1
// (R7), T14 reg-staging (R8: disaster) -- all null or worse. This gload_lds
// single-buffer form is the proven optimum of the explored space.
// R9: proj UN-fused (R6 counters: proj-fused = 5x54.8us top offenders,
// 1.5 blk/CU latency-bound; unfused proj never in any top-5 + ln only 8us).
// ffn2+ln1 fusion kept (not in top-5; saves a 63MB re-read + 4 ln launches).
// EPI: 1=bias+gelu->bf16, 2=bias+residual->f32, 3=bias+gelu->f32,
//      4=bias->bf16, 5=bias+residual->f32 x AND fused row-LN->bf16 Cb
//      (EPI=5 requires BN == N; NT=10, MT=2).
template <int EPI, int NT, int MT>
__global__ __launch_bounds__(256, 3) void gemm_mfma(
    const ushort_t* __restrict__ A, const ushort_t* __restrict__ W,
    const float* __restrict__ bias, const float* __restrict__ R,
    float* __restrict__ C, ushort_t* __restrict__ Cb,
    const float* __restrict__ lnw, const float* __restrict__ lnb,
    int M, int N, int K) {
  constexpr int BM_ = MT * 32, BK = 64;
  constexpr int BN = 32 * NT;
  constexpr int AR = BM_ / 32;   // A staging rounds (32 rows each)
  constexpr int WR = BN / 32;    // W staging rounds
  __shared__ __align__(16) ushort_t As[BM_ * BK];
  __shared__ __align__(16) ushort_t Ws[BN * BK];
  __shared__ float psum[2][(EPI == 5) ? BM_ : 4];  // fused-LN partials
  __shared__ float psq[2][(EPI == 5) ? BM_ : 4];

  int tid = threadIdx.x;
  int lane = tid & 63;
  int wv = tid >> 6;
  int wvM = wv & 1, wvN = wv >> 1;
  int laneM = lane & 15;
  int kgrp = lane >> 4;
  int sA = laneM & 7;

  // T1 XCD-aware remap (requires nbx % 8 == 0; bijective)
  int nbx = gridDim.x;
  int lid = blockIdx.x + nbx * blockIdx.y;
  int nchunk = nbx >> 3;
  int mb = (lid & 7) * nchunk + ((lid >> 3) % nchunk);
  int nb = (lid >> 3) / nchunk;
  int m0 = mb * BM_;
  int n0 = nb * BN;

  facc4 acc[MT][NT];
#pragma unroll
  for (int mt = 0; mt < MT; mt++)
#pragma unroll
    for (int nt = 0; nt < NT; nt++) acc[mt][nt] = (facc4){0.f, 0.f, 0.f, 0.f};

  int srow = tid >> 3;
  int jg = (tid & 7) ^ (srow & 7);
  const ushort_t* Ag = A + (size_t)(m0 + srow) * K + jg * 8;
  const ushort_t* Wg = W + (size_t)(n0 + srow) * K + jg * 8;

  for (int k0 = 0; k0 < K; k0 += BK) {
#pragma unroll
    for (int r = 0; r < AR; r++)
      GLOAD_LDS16(Ag + (size_t)r * 32 * K + k0, As + r * 2048 + tid * 8);
#pragma unroll
    for (int r = 0; r < WR; r++)
      GLOAD_LDS16(Wg + (size_t)r * 32 * K + k0, Ws + r * 2048 + tid * 8);
    __syncthreads();   // drains vmcnt (global_load_lds) + orders LDS use
#pragma unroll
    for (int kc = 0; kc < 2; kc++) {
      int jcol = ((kc * 4 + kgrp) ^ sA) * 8;
      bfrag8 af[MT];
#pragma unroll
      for (int mt = 0; mt < MT; mt++) {
        int row = wvM * (MT * 16) + mt * 16 + laneM;
        af[mt] = *(const bfrag8*)&As[row * 64 + jcol];
      }
#pragma unroll
      for (int nt = 0; nt < NT; nt++) {
        int nrow = wvN * (BN / 2) + nt * 16 + laneM;
        bfrag8 bf = *(const bfrag8*)&Ws[nrow * 64 + jcol];
#pragma unroll
        for (int mt = 0; mt < MT; mt++)
          acc[mt][nt] = __builtin_amdgcn_mfma_f32_16x16x32_bf16(
              bf, af[mt], acc[mt][nt], 0, 0, 0);   // swapped: D[n][m]
      }
    }
    __syncthreads();   // protect LDS from next iteration's staging
  }

  if constexpr (EPI == 5) {
    // ---- fused epilogue: v = acc + bias + residual; x=v; Cb=LN(v) ----
    float rs[MT], rq[MT];
#pragma unroll
    for (int mt = 0; mt < MT; mt++) { rs[mt] = 0.f; rq[mt] = 0.f; }
#pragma unroll
    for (int mt = 0; mt < MT; mt++) {
      int m = m0 + wvM * (MT * 16) + mt * 16 + laneM;
#pragma unroll
      for (int nt = 0; nt < NT; nt++) {
        int n = n0 + wvN * (BN / 2) + nt * 16 + kgrp * 4;
        float4 bv = *(const float4*)(bias + n);
        size_t off = (size_t)m * N + n;
        float4 r = *(const float4*)(R + off);
        facc4 a = acc[mt][nt];
        a[0] += bv.x + r.x; a[1] += bv.y + r.y;
        a[2] += bv.z + r.z; a[3] += bv.w + r.w;
        acc[mt][nt] = a;
        rs[mt] += a[0] + a[1] + a[2] + a[3];
        rq[mt] += a[0] * a[0] + a[1] * a[1] + a[2] * a[2] + a[3] * a[3];
      }
    }
    // reduce across the 4 kgrp lanes holding the same row (lanes ^16, ^32)
#pragma unroll
    for (int mt = 0; mt < MT; mt++) {
      rs[mt] += __shfl_xor(rs[mt], 16, 64);
      rs[mt] += __shfl_xor(rs[mt], 32, 64);
      rq[mt] += __shfl_xor(rq[mt], 16, 64);
      rq[mt] += __shfl_xor(rq[mt], 32, 64);
    }
    if (lane < 16) {   // kgrp == 0 lanes publish per-wvN row partials
#pragma unroll
      for (int mt = 0; mt < MT; mt++) {
        int lr = wvM * (MT * 16) + mt * 16 + laneM;
        psum[wvN][lr] = rs[mt];
        psq[wvN][lr] = rq[mt];
      }
    }
    __syncthreads();
#pragma unroll
    for (int mt = 0; mt < MT; mt++) {
      int lr = wvM * (MT * 16) + mt * 16 + laneM;
      int m = m0 + lr;
      float ts = psum[0][lr] + psum[1][lr];
      float tq = psq[0][lr] + psq[1][lr];
      float mean = ts * (1.0f / (float)D);
      float var = tq * (1.0f / (float)D) - mean * mean;
      float inv = 1.0f / sqrtf(var + 1e-5f);
#pragma unroll
      for (int nt = 0; nt < NT; nt++) {
        int n = n0 + wvN * (BN / 2) + nt * 16 + kgrp * 4;
        size_t off = (size_t)m * N + n;
        facc4 a = acc[mt][nt];
        *(float4*)(C + off) = (float4){a[0], a[1], a[2], a[3]};
        float4 w4 = *(const float4*)(lnw + n);
        float4 b4 = *(const float4*)(lnb + n);
        ushort4 o;
        o.x = f2b((a[0] - mean) * inv * w4.x + b4.x);
        o.y = f2b((a[1] - mean) * inv * w4.y + b4.y);
        o.z = f2b((a[2] - mean) * inv * w4.z + b4.z);
        o.w = f2b((a[3] - mean) * inv * w4.w + b4.w);
        *(ushort4*)(Cb + off) = o;
      }
    }
  } else {
    // epilogue (transposed D): m = laneM-based, n = kgrp*4 + reg
#pragma unroll
    for (int mt = 0; mt < MT; mt++) {
      int m = m0 + wvM * (MT * 16) + mt * 16 + laneM;
#pragma unroll
      for (int nt = 0; nt < NT; nt++) {
        int n = n0 + wvN * (BN / 2) + nt * 16 + kgrp * 4;
        float4 bv = *(const float4*)(bias + n);
        facc4 a = acc[mt][nt];
        float v0 = a[0] + bv.x, v1 = a[1] + bv.y, v2 = a[2] + bv.z,
              v3 = a[3] + bv.w;
        size_t off = (size_t)m * N + n;
        if constexpr (EPI == 1) {
          ushort4 o;
          o.x = f2b(gelu_fast(v0)); o.y = f2b(gelu_fast(v1));
          o.z = f2b(gelu_fast(v2)); o.w = f2b(gelu_fast(v3));
          *(ushort4*)(Cb + off) = o;
        } else if constexpr (EPI == 2) {
          float4 r = *(const float4*)(R + off);
          float4 o = {v0 + r.x, v1 + r.y, v2 + r.z, v3 + r.w};
          *(float4*)(C + off) = o;
        } else if constexpr (EPI == 3) {
          float4 o = {gelu_fast(v0), gelu_fast(v1), gelu_fast(v2),
                      gelu_fast(v3)};
          *(float4*)(C + off) = o;
        } else {  // EPI == 4
          ushort4 o;
          o.x = f2b(v0); o.y = f2b(v1); o.z = f2b(v2); o.w = f2b(v3);
          *(ushort4*)(Cb + off) = o;
        }
      }
    }
  }
}

// ---------------- attention v2: one block per (b,h), conflict-free LDS -------
__global__ __launch_bounds__(256) void attn_kernel(
    const ushort_t* __restrict__ qkv, ushort_t* __restrict__ o) {
  int b = blockIdx.x >> 3;
  int h = blockIdx.x & 7;
  __shared__ __align__(16) float q[S][44];
  __shared__ __align__(16) float v[S][44];
  __shared__ __align__(16) float kT[DH][28];
  __shared__ __align__(16) float sc[S][28];
  int tid = threadIdx.x;
  const ushort_t* base = qkv + (size_t)b * S * (3 * D) + h * DH;

  for (int idx = tid; idx < 720; idx += 256) {
    int t = idx / 240;          // 0=q 1=k 2=v
    int r = idx % 240;
    int s = r / 10, dg = r % 10;
    ushort4 u = *(const ushort4*)(base + (size_t)s * (3 * D) + t * D + dg * 4);
    float4 f = {b2f(u.x), b2f(u.y), b2f(u.z), b2f(u.w)};
    if (t == 0) {
      *(float4*)&q[s][dg * 4] = f;
    } else if (t == 2) {
      *(float4*)&v[s][dg * 4] = f;
    } else {
      kT[dg * 4 + 0][s] = f.x;
      kT[dg * 4 + 1][s] = f.y;
      kT[dg * 4 + 2][s] = f.z;
      kT[dg * 4 + 3][s] = f.w;
    }
  }
  __syncthreads();

  if (tid < 144) {
    int i = tid / 6, jg = tid % 6;
    facc4 acc = {0.f, 0.f, 0.f, 0.f};
#pragma unroll
    for (int d = 0; d < DH; d++) {
      float qv = q[i][d];
      float4 kv = *(const float4*)&kT[d][jg * 4];
      acc[0] += qv * kv.x; acc[1] += qv * kv.y;
      acc[2] += qv * kv.z; acc[3] += qv * kv.w;
    }
    const float sca = 0.15811388300841897f;  // 1/sqrt(40)
    float4 ov = {acc[0] * sca, acc[1] * sca, acc[2] * sca, acc[3] * sca};
    *(float4*)&sc[i][jg * 4] = ov;
  }
  __syncthreads();

  if (tid < S) {
    float mx = -1e30f;
#pragma unroll
    for (int j = 0; j < S; j++) mx = fmaxf(mx, sc[tid][j]);
    float sum = 0.f;
#pragma unroll
    for (int j = 0; j < S; j++) {
      float e = __expf(sc[tid][j] - mx);
      sc[tid][j] = e;
      sum += e;
    }
    float rr = 1.0f / sum;
#pragma unroll
    for (int j = 0; j < S; j++) sc[tid][j] *= rr;
  }
  __syncthreads();

  if (tid < 240) {
    int i = tid / 10, dg = tid % 10;
    facc4 acc = {0.f, 0.f, 0.f, 0.f};
#pragma unroll
    for (int j = 0; j < S; j++) {
      float p = sc[i][j];
      float4 vv = *(const float4*)&v[j][dg * 4];
      acc[0] += p * vv.x; acc[1] += p * vv.y;
      acc[2] += p * vv.z; acc[3] += p * vv.w;
    }
    ushort4 ov;
    ov.x = f2b(acc[0]); ov.y = f2b(acc[1]);
    ov.z = f2b(acc[2]); ov.w = f2b(acc[3]);
    *(ushort4*)(o + (size_t)b * S * D + (size_t)i * D + h * DH + dg * 4) = ov;
  }
}

// ---------------- head tail: c = g@Wh2^T+bh2 ; cheb ; sigmoid ----------------
__global__ __launch_bounds__(256) void head_cheb(
    const float* __restrict__ g, const float* __restrict__ Wh2,
    const float* __restrict__ bh2, const float* __restrict__ k_norm,
    float* __restrict__ out) {
  int b = blockIdx.x;
  __shared__ float gs[D];
  __shared__ float cs[NM1];
  int tid = threadIdx.x;
  for (int i = tid; i < D; i += 256) gs[i] = g[(size_t)b * D + i];
  __syncthreads();
  if (tid < NM1) {
    const float* wr = Wh2 + (size_t)tid * D;
    float s = bh2[tid];
    for (int d = 0; d < D; d++) s += gs[d] * wr[d];
    cs[tid] = s;
  }
  __syncthreads();
  for (int t = tid; t < T_SZ; t += 256) {
    float xv = k_norm[(size_t)b * T_SZ + t];
    float tp = 1.f, tc = xv;
    float acc = cs[0] + cs[1] * xv;
#pragma unroll
    for (int n = 2; n < NM1; n++) {
      float tn = 2.f * xv * tc - tp;
      acc += cs[n] * tn;
      tp = tc;
      tc = tn;
    }
    out[(size_t)b * T_SZ + t] = 1.f / (1.f + expf(-acc));
  }
}

extern "C" void kernel_launch(void* const* d_in, const int* in_sizes, int n_in,
                              void* d_out, int out_size, void* d_ws,
                              size_t ws_size, hipStream_t stream) {
  const float* k_norm = (const float*)d_in[0];
  const float* ctx    = (const float*)d_in[1];
  const float* W_e    = (const float*)d_in[2];
  const float* b_e    = (const float*)d_in[3];
  const float* cls    = (const float*)d_in[4];
  const float* ln1_w  = (const float*)d_in[5];
  const float* ln1_b  = (const float*)d_in[6];
  const float* W_in   = (const float*)d_in[7];
  const float* b_in   = (const float*)d_in[8];
  const float* W_out  = (const float*)d_in[9];
  const float* b_out  = (const float*)d_in[10];
  const float* ln2_w  = (const float*)d_in[11];
  const float* ln2_b  = (const float*)d_in[12];
  const float* W1     = (const float*)d_in[13];
  const float* b1     = (const float*)d_in[14];
  const float* W2     = (const float*)d_in[15];
  const float* b2     = (const float*)d_in[16];
  const float* hln_w  = (const float*)d_in[17];
  const float* hln_b  = (const float*)d_in[18];
  const float* Wh1    = (const float*)d_in[19];
  const float* bh1    = (const float*)d_in[20];
  const float* Wh2    = (const float*)d_in[21];
  const float* bh2    = (const float*)d_in[22];
  float* out = (float*)d_out;

  float* x = (float*)d_ws;
  ushort_t* hbuf = (ushort_t*)(x + (size_t)M_ROWS * D);
  ushort_t* big = hbuf + (size_t)M_ROWS * D;
  ushort_t* wb_in = big + (size_t)M_ROWS * FF;
  ushort_t* wb_out = wb_in + (size_t)L_LAYERS * 3 * D * D;
  ushort_t* wb1 = wb_out + (size_t)L_LAYERS * D * D;
  ushort_t* wb2 = wb1 + (size_t)L_LAYERS * FF * D;
  ushort_t* wbh1 = wb2 + (size_t)L_LAYERS * D * FF;
  ushort_t* hcls = wbh1 + (size_t)D * D;
  float* ghead = (float*)(hcls + (size_t)B_SZ * D);
  // attn output lives in the tail of big (cols 960..1280 region, disjoint
  // from the qkv output in cols 0..960; both dead once ffn1 overwrites big)
  ushort_t* abuf = big + (size_t)M_ROWS * 960;

  conv_all<<<6100, 256, 0, stream>>>(W_in, W_out, W1, W2, Wh1, wb_in);

  // embed + ln1(layer 0): writes x (f32) and hbuf = ln1_0(x) (bf16)
  embed_ln<<<M_ROWS / 4, 256, 0, stream>>>(ctx, W_e, b_e, cls, ln1_w, ln1_b,
                                           x, hbuf);

  for (int l = 0; l < L_LAYERS; l++) {
    gemm_mfma<4, 5, 4><<<dim3(M_ROWS / 128, (3 * D) / 160), 256, 0, stream>>>(
        hbuf, wb_in + (size_t)l * 3 * D * D, b_in + (size_t)l * 3 * D, nullptr,
        nullptr, big, nullptr, nullptr, M_ROWS, 3 * D, D);
    attn_kernel<<<B_SZ * H, 256, 0, stream>>>(big, abuf);
    // proj + residual -> x (f32); unfused (R9): 768 blocks, never a top-5
    gemm_mfma<2, 5, 2><<<dim3(M_ROWS / 64, D / 160), 256, 0, stream>>>(
        abuf, wb_out + (size_t)l * D * D, b_out + (size_t)l * D, x, x, nullptr,
        nullptr, nullptr, M_ROWS, D, D);
    ln_kernel<<<M_ROWS / 4, 256, 0, stream>>>(x, ln2_w + l * D, ln2_b + l * D,
                                              hbuf, D, D);
    gemm_mfma<1, 5, 4><<<dim3(M_ROWS / 128, FF / 160), 256, 0, stream>>>(
        hbuf, wb1 + (size_t)l * FF * D, b1 + (size_t)l * FF, nullptr, nullptr,
        big, nullptr, nullptr, M_ROWS, FF, D);
    if (l + 1 < L_LAYERS) {
      // ffn2 + residual + fused ln1(l+1) -> x (f32) and hbuf (bf16)
      gemm_mfma<5, 10, 2><<<dim3(M_ROWS / 64, 1), 256, 0, stream>>>(
          big, wb2 + (size_t)l * D * FF, b2 + (size_t)l * D, x, x, hbuf,
          ln1_w + (size_t)(l + 1) * D, ln1_b + (size_t)(l + 1) * D,
          M_ROWS, D, FF);
    } else {
      gemm_mfma<2, 5, 2><<<dim3(M_ROWS / 64, D / 160), 256, 0, stream>>>(
          big, wb2 + (size_t)l * D * FF, b2 + (size_t)l * D, x, x, nullptr,
          nullptr, nullptr, M_ROWS, D, FF);
    }
  }

  ln_kernel<<<B_SZ / 4, 256, 0, stream>>>(x, hln_w, hln_b, hcls, S * D, D);
  gemm_mfma<3, 5, 2><<<dim3(B_SZ / 64, D / 160), 256, 0, stream>>>(
      hcls, wbh1, bh1, nullptr, ghead, nullptr, nullptr, nullptr, B_SZ, D, D);
  head_cheb<<<B_SZ, 256, 0, stream>>>(ghead, Wh2, bh2, k_norm, out);
}

// Round 10
// 1023.860 us; speedup vs baseline: 2.1911x; 1.0049x over previous
//
#include <hip/hip_runtime.h>
#include <hip/hip_bf16.h>
#include <math.h>

// Problem constants
#define B_SZ 1024
#define T_SZ 512
#define CTX_N 23
#define D 320
#define L_LAYERS 5
#define H 8
#define FF 1280
#define NM1 49      // NMODES + 1
#define S 24        // CTX + 1
#define DH 40       // D / H
#define M_ROWS (B_SZ * S)   // 24576

typedef unsigned short ushort_t;
typedef __attribute__((ext_vector_type(8))) short bfrag8;   // 8 bf16 (4 VGPRs)
typedef __attribute__((ext_vector_type(4))) float facc4;    // 4 fp32 acc

__device__ __forceinline__ float wave_sum(float v) {
#pragma unroll
  for (int off = 32; off > 0; off >>= 1) v += __shfl_xor(v, off, 64);
  return v;
}

// tanh-form gelu (max |err| ~3e-4 << bf16 quantum, safe at +-inf)
__device__ __forceinline__ float gelu_fast(float x) {
  float t = __builtin_amdgcn_exp2f(x * (2.30211416f + 0.10294404f * x * x));
  return x - x * __builtin_amdgcn_rcpf(t + 1.0f);
}

__device__ __forceinline__ ushort_t f2b(float x) {
  __hip_bfloat16 h = __float2bfloat16(x);
  return *reinterpret_cast<ushort_t*>(&h);
}

__device__ __forceinline__ float b2f(ushort_t u) {
  __hip_bfloat16 h = *reinterpret_cast<__hip_bfloat16*>(&u);
  return __bfloat162float(h);
}

#define GLOAD_LDS16(g, l)                                     \
  __builtin_amdgcn_global_load_lds(                           \
      (const __attribute__((address_space(1))) void*)(g),     \
      (__attribute__((address_space(3))) void*)(l), 16, 0, 0)

// ---------------- all-weights f32 -> bf16 (dst regions contiguous) -----------
__global__ __launch_bounds__(256) void conv_all(
    const float* __restrict__ w_in, const float* __restrict__ w_out,
    const float* __restrict__ w1, const float* __restrict__ w2,
    const float* __restrict__ wh1, ushort_t* __restrict__ dst) {
  int i = blockIdx.x * 256 + threadIdx.x;
  const float* src;
  int off;
  if (i < 384000)       { src = w_in;  off = i; }
  else if (i < 512000)  { src = w_out; off = i - 384000; }
  else if (i < 1024000) { src = w1;    off = i - 512000; }
  else if (i < 1536000) { src = w2;    off = i - 1024000; }
  else                  { src = wh1;   off = i - 1536000; }
  float4 v = ((const float4*)src)[off];
  ushort4 o;
  o.x = f2b(v.x); o.y = f2b(v.y); o.z = f2b(v.z); o.w = f2b(v.w);
  ((ushort4*)dst)[i] = o;
}

// ---------------- embed + LN1(layer0) fused: one wave per row ----------------
// Writes x (residual stream, f32) AND hbuf = ln1_0(x) (bf16) in one pass.
__global__ __launch_bounds__(256) void embed_ln(
    const float* __restrict__ ctx, const float* __restrict__ W_e,
    const float* __restrict__ b_e, const float* __restrict__ cls,
    const float* __restrict__ lnw, const float* __restrict__ lnb,
    float* __restrict__ x, ushort_t* __restrict__ y) {
  int wv = threadIdx.x >> 6;
  int lane = threadIdx.x & 63;
  int row = blockIdx.x * 4 + wv;   // row = b*S + s
  int s = row % S;
  int b = row / S;
  float cv = (s == 0) ? 0.f : ctx[b * CTX_N + (s - 1)];
  float v[5];
#pragma unroll
  for (int i = 0; i < 5; i++) {
    int d = lane + 64 * i;
    v[i] = (s == 0) ? cls[d] : cv * W_e[d] + b_e[d];
  }
  float* xr = x + (size_t)row * D;
#pragma unroll
  for (int i = 0; i < 5; i++) xr[lane + 64 * i] = v[i];
  float sm = v[0] + v[1] + v[2] + v[3] + v[4];
  sm = wave_sum(sm);
  float m = sm * (1.0f / (float)D);
  float sq = 0.f;
#pragma unroll
  for (int i = 0; i < 5; i++) { float d0 = v[i] - m; sq += d0 * d0; }
  sq = wave_sum(sq);
  float inv = 1.0f / sqrtf(sq * (1.0f / (float)D) + 1e-5f);
  ushort_t* yr = y + (size_t)row * D;
#pragma unroll
  for (int i = 0; i < 5; i++) {
    int d = lane + 64 * i;
    yr[d] = f2b((v[i] - m) * inv * lnw[d] + lnb[d]);
  }
}

// ---------------- layernorm: fp32 in, bf16 out, one wave per row -------------
__global__ __launch_bounds__(256) void ln_kernel(
    const float* __restrict__ X, const float* __restrict__ w,
    const float* __restrict__ b, ushort_t* __restrict__ Y,
    int inStride, int outStride) {
  int wv = threadIdx.x >> 6;
  int lane = threadIdx.x & 63;
  int row = blockIdx.x * 4 + wv;
  const float* xr = X + (size_t)row * inStride;
  float v[5];
#pragma unroll
  for (int i = 0; i < 5; i++) v[i] = xr[lane + 64 * i];
  float s = v[0] + v[1] + v[2] + v[3] + v[4];
  s = wave_sum(s);
  float m = s * (1.0f / (float)D);
  float sq = 0.f;
#pragma unroll
  for (int i = 0; i < 5; i++) { float d0 = v[i] - m; sq += d0 * d0; }
  sq = wave_sum(sq);
  float inv = 1.0f / sqrtf(sq * (1.0f / (float)D) + 1e-5f);
  ushort_t* yr = Y + (size_t)row * outStride;
#pragma unroll
  for (int i = 0; i < 5; i++) {
    int d = lane + 64 * i;
    yr[d] = f2b((v[i] - m) * inv * w[d] + b[d]);
  }
}

// ---------------- bf16 MFMA GEMM (R6 form: gload_lds, single buffer) ---------
// BM=MT*32, BK=64, BN=32*NT. 256 threads = 4 waves (2x2). Single LDS buffer,
// 2 __syncthreads/step. Swizzled K-contiguous layout (chunk j of row r at
// slot j^(r&7)): conflict-free (measured 0). Swapped MFMA -> D[n][m].
// T1 XCD remap (nbx % 8 == 0; bijective).
// Session ledger: MT/tile shape (R1), XCD swizzle (R2), drain-0 dbuf (R3),
// raw-barrier counted-vmcnt (R4/R5: container hangs), occupancy via MT=1
// (R7), T14 reg-staging (R8: disaster), proj un-fuse (R9: -34us vs R6) --
// all null or worse. gload_lds single-buffer + fusion is the proven optimum.
// R10: ffn2 UN-fused. R9 counters identified the 53.8us/49.4MB-FETCH top
// offenders as the ffn2-fused EPI5 kernels (grid 384, 20 K-steps, 1.5
// blk/CU latency-bound; R7 proved not TLP-fixable). Unfused ffn2 (EPI2,
// grid 768, 10 K-steps) never appeared in any top-5; ln costs 8us.
// proj stays FUSED (R6 994 < R9 1028 with proj unfused).
// EPI: 1=bias+gelu->bf16, 2=bias+residual->f32, 3=bias+gelu->f32,
//      4=bias->bf16, 5=bias+residual->f32 x AND fused row-LN->bf16 Cb
//      (EPI=5 requires BN == N; NT=10, MT=2).
template <int EPI, int NT, int MT>
__global__ __launch_bounds__(256, 3) void gemm_mfma(
    const ushort_t* __restrict__ A, const ushort_t* __restrict__ W,
    const float* __restrict__ bias, const float* __restrict__ R,
    float* __restrict__ C, ushort_t* __restrict__ Cb,
    const float* __restrict__ lnw, const float* __restrict__ lnb,
    int M, int N, int K) {
  constexpr int BM_ = MT * 32, BK = 64;
  constexpr int BN = 32 * NT;
  constexpr int AR = BM_ / 32;   // A staging rounds (32 rows each)
  constexpr int WR = BN / 32;    // W staging rounds
  __shared__ __align__(16) ushort_t As[BM_ * BK];
  __shared__ __align__(16) ushort_t Ws[BN * BK];
  __shared__ float psum[2][(EPI == 5) ? BM_ : 4];  // fused-LN partials
  __shared__ float psq[2][(EPI == 5) ? BM_ : 4];

  int tid = threadIdx.x;
  int lane = tid & 63;
  int wv = tid >> 6;
  int wvM = wv & 1, wvN = wv >> 1;
  int laneM = lane & 15;
  int kgrp = lane >> 4;
  int sA = laneM & 7;

  // T1 XCD-aware remap (requires nbx % 8 == 0; bijective)
  int nbx = gridDim.x;
  int lid = blockIdx.x + nbx * blockIdx.y;
  int nchunk = nbx >> 3;
  int mb = (lid & 7) * nchunk + ((lid >> 3) % nchunk);
  int nb = (lid >> 3) / nchunk;
  int m0 = mb * BM_;
  int n0 = nb * BN;

  facc4 acc[MT][NT];
#pragma unroll
  for (int mt = 0; mt < MT; mt++)
#pragma unroll
    for (int nt = 0; nt < NT; nt++) acc[mt][nt] = (facc4){0.f, 0.f, 0.f, 0.f};

  int srow = tid >> 3;
  int jg = (tid & 7) ^ (srow & 7);
  const ushort_t* Ag = A + (size_t)(m0 + srow) * K + jg * 8;
  const ushort_t* Wg = W + (size_t)(n0 + srow) * K + jg * 8;

  for (int k0 = 0; k0 < K; k0 += BK) {
#pragma unroll
    for (int r = 0; r < AR; r++)
      GLOAD_LDS16(Ag + (size_t)r * 32 * K + k0, As + r * 2048 + tid * 8);
#pragma unroll
    for (int r = 0; r < WR; r++)
      GLOAD_LDS16(Wg + (size_t)r * 32 * K + k0, Ws + r * 2048 + tid * 8);
    __syncthreads();   // drains vmcnt (global_load_lds) + orders LDS use
#pragma unroll
    for (int kc = 0; kc < 2; kc++) {
      int jcol = ((kc * 4 + kgrp) ^ sA) * 8;
      bfrag8 af[MT];
#pragma unroll
      for (int mt = 0; mt < MT; mt++) {
        int row = wvM * (MT * 16) + mt * 16 + laneM;
        af[mt] = *(const bfrag8*)&As[row * 64 + jcol];
      }
#pragma unroll
      for (int nt = 0; nt < NT; nt++) {
        int nrow = wvN * (BN / 2) + nt * 16 + laneM;
        bfrag8 bf = *(const bfrag8*)&Ws[nrow * 64 + jcol];
#pragma unroll
        for (int mt = 0; mt < MT; mt++)
          acc[mt][nt] = __builtin_amdgcn_mfma_f32_16x16x32_bf16(
              bf, af[mt], acc[mt][nt], 0, 0, 0);   // swapped: D[n][m]
      }
    }
    __syncthreads();   // protect LDS from next iteration's staging
  }

  if constexpr (EPI == 5) {
    // ---- fused epilogue: v = acc + bias + residual; x=v; Cb=LN(v) ----
    float rs[MT], rq[MT];
#pragma unroll
    for (int mt = 0; mt < MT; mt++) { rs[mt] = 0.f; rq[mt] = 0.f; }
#pragma unroll
    for (int mt = 0; mt < MT; mt++) {
      int m = m0 + wvM * (MT * 16) + mt * 16 + laneM;
#pragma unroll
      for (int nt = 0; nt < NT; nt++) {
        int n = n0 + wvN * (BN / 2) + nt * 16 + kgrp * 4;
        float4 bv = *(const float4*)(bias + n);
        size_t off = (size_t)m * N + n;
        float4 r = *(const float4*)(R + off);
        facc4 a = acc[mt][nt];
        a[0] += bv.x + r.x; a[1] += bv.y + r.y;
        a[2] += bv.z + r.z; a[3] += bv.w + r.w;
        acc[mt][nt] = a;
        rs[mt] += a[0] + a[1] + a[2] + a[3];
        rq[mt] += a[0] * a[0] + a[1] * a[1] + a[2] * a[2] + a[3] * a[3];
      }
    }
    // reduce across the 4 kgrp lanes holding the same row (lanes ^16, ^32)
#pragma unroll
    for (int mt = 0; mt < MT; mt++) {
      rs[mt] += __shfl_xor(rs[mt], 16, 64);
      rs[mt] += __shfl_xor(rs[mt], 32, 64);
      rq[mt] += __shfl_xor(rq[mt], 16, 64);
      rq[mt] += __shfl_xor(rq[mt], 32, 64);
    }
    if (lane < 16) {   // kgrp == 0 lanes publish per-wvN row partials
#pragma unroll
      for (int mt = 0; mt < MT; mt++) {
        int lr = wvM * (MT * 16) + mt * 16 + laneM;
        psum[wvN][lr] = rs[mt];
        psq[wvN][lr] = rq[mt];
      }
    }
    __syncthreads();
#pragma unroll
    for (int mt = 0; mt < MT; mt++) {
      int lr = wvM * (MT * 16) + mt * 16 + laneM;
      int m = m0 + lr;
      float ts = psum[0][lr] + psum[1][lr];
      float tq = psq[0][lr] + psq[1][lr];
      float mean = ts * (1.0f / (float)D);
      float var = tq * (1.0f / (float)D) - mean * mean;
      float inv = 1.0f / sqrtf(var + 1e-5f);
#pragma unroll
      for (int nt = 0; nt < NT; nt++) {
        int n = n0 + wvN * (BN / 2) + nt * 16 + kgrp * 4;
        size_t off = (size_t)m * N + n;
        facc4 a = acc[mt][nt];
        *(float4*)(C + off) = (float4){a[0], a[1], a[2], a[3]};
        float4 w4 = *(const float4*)(lnw + n);
        float4 b4 = *(const float4*)(lnb + n);
        ushort4 o;
        o.x = f2b((a[0] - mean) * inv * w4.x + b4.x);
        o.y = f2b((a[1] - mean) * inv * w4.y + b4.y);
        o.z = f2b((a[2] - mean) * inv * w4.z + b4.z);
        o.w = f2b((a[3] - mean) * inv * w4.w + b4.w);
        *(ushort4*)(Cb + off) = o;
      }
    }
  } else {
    // epilogue (transposed D): m = laneM-based, n = kgrp*4 + reg
#pragma unroll
    for (int mt = 0; mt < MT; mt++) {
      int m = m0 + wvM * (MT * 16) + mt * 16 + laneM;
#pragma unroll
      for (int nt = 0; nt < NT; nt++) {
        int n = n0 + wvN * (BN / 2) + nt * 16 + kgrp * 4;
        float4 bv = *(const float4*)(bias + n);
        facc4 a = acc[mt][nt];
        float v0 = a[0] + bv.x, v1 = a[1] + bv.y, v2 = a[2] + bv.z,
              v3 = a[3] + bv.w;
        size_t off = (size_t)m * N + n;
        if constexpr (EPI == 1) {
          ushort4 o;
          o.x = f2b(gelu_fast(v0)); o.y = f2b(gelu_fast(v1));
          o.z = f2b(gelu_fast(v2)); o.w = f2b(gelu_fast(v3));
          *(ushort4*)(Cb + off) = o;
        } else if constexpr (EPI == 2) {
          float4 r = *(const float4*)(R + off);
          float4 o = {v0 + r.x, v1 + r.y, v2 + r.z, v3 + r.w};
          *(float4*)(C + off) = o;
        } else if constexpr (EPI == 3) {
          float4 o = {gelu_fast(v0), gelu_fast(v1), gelu_fast(v2),
                      gelu_fast(v3)};
          *(float4*)(C + off) = o;
        } else {  // EPI == 4
          ushort4 o;
          o.x = f2b(v0); o.y = f2b(v1); o.z = f2b(v2); o.w = f2b(v3);
          *(ushort4*)(Cb + off) = o;
        }
      }
    }
  }
}

// ---------------- attention v2: one block per (b,h), conflict-free LDS -------
__global__ __launch_bounds__(256) void attn_kernel(
    const ushort_t* __restrict__ qkv, ushort_t* __restrict__ o) {
  int b = blockIdx.x >> 3;
  int h = blockIdx.x & 7;
  __shared__ __align__(16) float q[S][44];
  __shared__ __align__(16) float v[S][44];
  __shared__ __align__(16) float kT[DH][28];
  __shared__ __align__(16) float sc[S][28];
  int tid = threadIdx.x;
  const ushort_t* base = qkv + (size_t)b * S * (3 * D) + h * DH;

  for (int idx = tid; idx < 720; idx += 256) {
    int t = idx / 240;          // 0=q 1=k 2=v
    int r = idx % 240;
    int s = r / 10, dg = r % 10;
    ushort4 u = *(const ushort4*)(base + (size_t)s * (3 * D) + t * D + dg * 4);
    float4 f = {b2f(u.x), b2f(u.y), b2f(u.z), b2f(u.w)};
    if (t == 0) {
      *(float4*)&q[s][dg * 4] = f;
    } else if (t == 2) {
      *(float4*)&v[s][dg * 4] = f;
    } else {
      kT[dg * 4 + 0][s] = f.x;
      kT[dg * 4 + 1][s] = f.y;
      kT[dg * 4 + 2][s] = f.z;
      kT[dg * 4 + 3][s] = f.w;
    }
  }
  __syncthreads();

  if (tid < 144) {
    int i = tid / 6, jg = tid % 6;
    facc4 acc = {0.f, 0.f, 0.f, 0.f};
#pragma unroll
    for (int d = 0; d < DH; d++) {
      float qv = q[i][d];
      float4 kv = *(const float4*)&kT[d][jg * 4];
      acc[0] += qv * kv.x; acc[1] += qv * kv.y;
      acc[2] += qv * kv.z; acc[3] += qv * kv.w;
    }
    const float sca = 0.15811388300841897f;  // 1/sqrt(40)
    float4 ov = {acc[0] * sca, acc[1] * sca, acc[2] * sca, acc[3] * sca};
    *(float4*)&sc[i][jg * 4] = ov;
  }
  __syncthreads();

  if (tid < S) {
    float mx = -1e30f;
#pragma unroll
    for (int j = 0; j < S; j++) mx = fmaxf(mx, sc[tid][j]);
    float sum = 0.f;
#pragma unroll
    for (int j = 0; j < S; j++) {
      float e = __expf(sc[tid][j] - mx);
      sc[tid][j] = e;
      sum += e;
    }
    float rr = 1.0f / sum;
#pragma unroll
    for (int j = 0; j < S; j++) sc[tid][j] *= rr;
  }
  __syncthreads();

  if (tid < 240) {
    int i = tid / 10, dg = tid % 10;
    facc4 acc = {0.f, 0.f, 0.f, 0.f};
#pragma unroll
    for (int j = 0; j < S; j++) {
      float p = sc[i][j];
      float4 vv = *(const float4*)&v[j][dg * 4];
      acc[0] += p * vv.x; acc[1] += p * vv.y;
      acc[2] += p * vv.z; acc[3] += p * vv.w;
    }
    ushort4 ov;
    ov.x = f2b(acc[0]); ov.y = f2b(acc[1]);
    ov.z = f2b(acc[2]); ov.w = f2b(acc[3]);
    *(ushort4*)(o + (size_t)b * S * D + (size_t)i * D + h * DH + dg * 4) = ov;
  }
}

// ---------------- head tail: c = g@Wh2^T+bh2 ; cheb ; sigmoid ----------------
__global__ __launch_bounds__(256) void head_cheb(
    const float* __restrict__ g, const float* __restrict__ Wh2,
    const float* __restrict__ bh2, const float* __restrict__ k_norm,
    float* __restrict__ out) {
  int b = blockIdx.x;
  __shared__ float gs[D];
  __shared__ float cs[NM1];
  int tid = threadIdx.x;
  for (int i = tid; i < D; i += 256) gs[i] = g[(size_t)b * D + i];
  __syncthreads();
  if (tid < NM1) {
    const float* wr = Wh2 + (size_t)tid * D;
    float s = bh2[tid];
    for (int d = 0; d < D; d++) s += gs[d] * wr[d];
    cs[tid] = s;
  }
  __syncthreads();
  for (int t = tid; t < T_SZ; t += 256) {
    float xv = k_norm[(size_t)b * T_SZ + t];
    float tp = 1.f, tc = xv;
    float acc = cs[0] + cs[1] * xv;
#pragma unroll
    for (int n = 2; n < NM1; n++) {
      float tn = 2.f * xv * tc - tp;
      acc += cs[n] * tn;
      tp = tc;
      tc = tn;
    }
    out[(size_t)b * T_SZ + t] = 1.f / (1.f + expf(-acc));
  }
}

extern "C" void kernel_launch(void* const* d_in, const int* in_sizes, int n_in,
                              void* d_out, int out_size, void* d_ws,
                              size_t ws_size, hipStream_t stream) {
  const float* k_norm = (const float*)d_in[0];
  const float* ctx    = (const float*)d_in[1];
  const float* W_e    = (const float*)d_in[2];
  const float* b_e    = (const float*)d_in[3];
  const float* cls    = (const float*)d_in[4];
  const float* ln1_w  = (const float*)d_in[5];
  const float* ln1_b  = (const float*)d_in[6];
  const float* W_in   = (const float*)d_in[7];
  const float* b_in   = (const float*)d_in[8];
  const float* W_out  = (const float*)d_in[9];
  const float* b_out  = (const float*)d_in[10];
  const float* ln2_w  = (const float*)d_in[11];
  const float* ln2_b  = (const float*)d_in[12];
  const float* W1     = (const float*)d_in[13];
  const float* b1     = (const float*)d_in[14];
  const float* W2     = (const float*)d_in[15];
  const float* b2     = (const float*)d_in[16];
  const float* hln_w  = (const float*)d_in[17];
  const float* hln_b  = (const float*)d_in[18];
  const float* Wh1    = (const float*)d_in[19];
  const float* bh1    = (const float*)d_in[20];
  const float* Wh2    = (const float*)d_in[21];
  const float* bh2    = (const float*)d_in[22];
  float* out = (float*)d_out;

  float* x = (float*)d_ws;
  ushort_t* hbuf = (ushort_t*)(x + (size_t)M_ROWS * D);
  ushort_t* big = hbuf + (size_t)M_ROWS * D;
  ushort_t* wb_in = big + (size_t)M_ROWS * FF;
  ushort_t* wb_out = wb_in + (size_t)L_LAYERS * 3 * D * D;
  ushort_t* wb1 = wb_out + (size_t)L_LAYERS * D * D;
  ushort_t* wb2 = wb1 + (size_t)L_LAYERS * FF * D;
  ushort_t* wbh1 = wb2 + (size_t)L_LAYERS * D * FF;
  ushort_t* hcls = wbh1 + (size_t)D * D;
  float* ghead = (float*)(hcls + (size_t)B_SZ * D);
  // attn output lives in the tail of big (cols 960..1280 region, disjoint
  // from the qkv output in cols 0..960; both dead once ffn1 overwrites big)
  ushort_t* abuf = big + (size_t)M_ROWS * 960;

  conv_all<<<6100, 256, 0, stream>>>(W_in, W_out, W1, W2, Wh1, wb_in);

  // embed + ln1(layer 0): writes x (f32) and hbuf = ln1_0(x) (bf16)
  embed_ln<<<M_ROWS / 4, 256, 0, stream>>>(ctx, W_e, b_e, cls, ln1_w, ln1_b,
                                           x, hbuf);

  for (int l = 0; l < L_LAYERS; l++) {
    gemm_mfma<4, 5, 4><<<dim3(M_ROWS / 128, (3 * D) / 160), 256, 0, stream>>>(
        hbuf, wb_in + (size_t)l * 3 * D * D, b_in + (size_t)l * 3 * D, nullptr,
        nullptr, big, nullptr, nullptr, M_ROWS, 3 * D, D);
    attn_kernel<<<B_SZ * H, 256, 0, stream>>>(big, abuf);
    // proj + residual + fused ln2 -> x (f32) and hbuf (bf16) [R6-proven]
    gemm_mfma<5, 10, 2><<<dim3(M_ROWS / 64, 1), 256, 0, stream>>>(
        abuf, wb_out + (size_t)l * D * D, b_out + (size_t)l * D, x, x, hbuf,
        ln2_w + (size_t)l * D, ln2_b + (size_t)l * D, M_ROWS, D, D);
    gemm_mfma<1, 5, 4><<<dim3(M_ROWS / 128, FF / 160), 256, 0, stream>>>(
        hbuf, wb1 + (size_t)l * FF * D, b1 + (size_t)l * FF, nullptr, nullptr,
        big, nullptr, nullptr, M_ROWS, FF, D);
    // ffn2 UN-fused (R10): EPI2, grid 768, 10 K-steps; + ln1(l+1) kernel
    gemm_mfma<2, 5, 2><<<dim3(M_ROWS / 64, D / 160), 256, 0, stream>>>(
        big, wb2 + (size_t)l * D * FF, b2 + (size_t)l * D, x, x, nullptr,
        nullptr, nullptr, M_ROWS, D, FF);
    if (l + 1 < L_LAYERS) {
      ln_kernel<<<M_ROWS / 4, 256, 0, stream>>>(
          x, ln1_w + (size_t)(l + 1) * D, ln1_b + (size_t)(l + 1) * D,
          hbuf, D, D);
    }
  }

  ln_kernel<<<B_SZ / 4, 256, 0, stream>>>(x, hln_w, hln_b, hcls, S * D, D);
  gemm_mfma<3, 5, 2><<<dim3(B_SZ / 64, D / 160), 256, 0, stream>>>(
      hcls, wbh1, bh1, nullptr, ghead, nullptr, nullptr, nullptr, B_SZ, D, D);
  head_cheb<<<B_SZ, 256, 0, stream>>>(ghead, Wh2, bh2, k_norm, out);
}

// Round 11
// 953.150 us; speedup vs baseline: 2.3537x; 1.0742x over previous
//
#include <hip/hip_runtime.h>
#include <hip/hip_bf16.h>
#include <math.h>

// Problem constants
#define B_SZ 1024
#define T_SZ 512
#define CTX_N 23
#define D 320
#define L_LAYERS 5
#define H 8
#define FF 1280
#define NM1 49      // NMODES + 1
#define S 24        // CTX + 1
#define DH 40       // D / H
#define M_ROWS (B_SZ * S)   // 24576

typedef unsigned short ushort_t;
typedef __attribute__((ext_vector_type(8))) short bfrag8;   // 8 bf16 (4 VGPRs)
typedef __attribute__((ext_vector_type(4))) float facc4;    // 4 fp32 acc

__device__ __forceinline__ float wave_sum(float v) {
#pragma unroll
  for (int off = 32; off > 0; off >>= 1) v += __shfl_xor(v, off, 64);
  return v;
}

// tanh-form gelu (max |err| ~3e-4 << bf16 quantum, safe at +-inf)
__device__ __forceinline__ float gelu_fast(float x) {
  float t = __builtin_amdgcn_exp2f(x * (2.30211416f + 0.10294404f * x * x));
  return x - x * __builtin_amdgcn_rcpf(t + 1.0f);
}

__device__ __forceinline__ ushort_t f2b(float x) {
  __hip_bfloat16 h = __float2bfloat16(x);
  return *reinterpret_cast<ushort_t*>(&h);
}

__device__ __forceinline__ float b2f(ushort_t u) {
  __hip_bfloat16 h = *reinterpret_cast<__hip_bfloat16*>(&u);
  return __bfloat162float(h);
}

#define GLOAD_LDS16(g, l)                                     \
  __builtin_amdgcn_global_load_lds(                           \
      (const __attribute__((address_space(1))) void*)(g),     \
      (__attribute__((address_space(3))) void*)(l), 16, 0, 0)

// ---------------- all-weights f32 -> bf16 (dst regions contiguous) -----------
__global__ __launch_bounds__(256) void conv_all(
    const float* __restrict__ w_in, const float* __restrict__ w_out,
    const float* __restrict__ w1, const float* __restrict__ w2,
    const float* __restrict__ wh1, ushort_t* __restrict__ dst) {
  int i = blockIdx.x * 256 + threadIdx.x;
  const float* src;
  int off;
  if (i < 384000)       { src = w_in;  off = i; }
  else if (i < 512000)  { src = w_out; off = i - 384000; }
  else if (i < 1024000) { src = w1;    off = i - 512000; }
  else if (i < 1536000) { src = w2;    off = i - 1024000; }
  else                  { src = wh1;   off = i - 1536000; }
  float4 v = ((const float4*)src)[off];
  ushort4 o;
  o.x = f2b(v.x); o.y = f2b(v.y); o.z = f2b(v.z); o.w = f2b(v.w);
  ((ushort4*)dst)[i] = o;
}

// ---------------- embed + LN1(layer0) fused: one wave per row ----------------
// Writes x (residual stream, f32) AND hbuf = ln1_0(x) (bf16) in one pass.
__global__ __launch_bounds__(256) void embed_ln(
    const float* __restrict__ ctx, const float* __restrict__ W_e,
    const float* __restrict__ b_e, const float* __restrict__ cls,
    const float* __restrict__ lnw, const float* __restrict__ lnb,
    float* __restrict__ x, ushort_t* __restrict__ y) {
  int wv = threadIdx.x >> 6;
  int lane = threadIdx.x & 63;
  int row = blockIdx.x * 4 + wv;   // row = b*S + s
  int s = row % S;
  int b = row / S;
  float cv = (s == 0) ? 0.f : ctx[b * CTX_N + (s - 1)];
  float v[5];
#pragma unroll
  for (int i = 0; i < 5; i++) {
    int d = lane + 64 * i;
    v[i] = (s == 0) ? cls[d] : cv * W_e[d] + b_e[d];
  }
  float* xr = x + (size_t)row * D;
#pragma unroll
  for (int i = 0; i < 5; i++) xr[lane + 64 * i] = v[i];
  float sm = v[0] + v[1] + v[2] + v[3] + v[4];
  sm = wave_sum(sm);
  float m = sm * (1.0f / (float)D);
  float sq = 0.f;
#pragma unroll
  for (int i = 0; i < 5; i++) { float d0 = v[i] - m; sq += d0 * d0; }
  sq = wave_sum(sq);
  float inv = 1.0f / sqrtf(sq * (1.0f / (float)D) + 1e-5f);
  ushort_t* yr = y + (size_t)row * D;
#pragma unroll
  for (int i = 0; i < 5; i++) {
    int d = lane + 64 * i;
    yr[d] = f2b((v[i] - m) * inv * lnw[d] + lnb[d]);
  }
}

// ---------------- layernorm: fp32 in, bf16 out, one wave per row -------------
__global__ __launch_bounds__(256) void ln_kernel(
    const float* __restrict__ X, const float* __restrict__ w,
    const float* __restrict__ b, ushort_t* __restrict__ Y,
    int inStride, int outStride) {
  int wv = threadIdx.x >> 6;
  int lane = threadIdx.x & 63;
  int row = blockIdx.x * 4 + wv;
  const float* xr = X + (size_t)row * inStride;
  float v[5];
#pragma unroll
  for (int i = 0; i < 5; i++) v[i] = xr[lane + 64 * i];
  float s = v[0] + v[1] + v[2] + v[3] + v[4];
  s = wave_sum(s);
  float m = s * (1.0f / (float)D);
  float sq = 0.f;
#pragma unroll
  for (int i = 0; i < 5; i++) { float d0 = v[i] - m; sq += d0 * d0; }
  sq = wave_sum(sq);
  float inv = 1.0f / sqrtf(sq * (1.0f / (float)D) + 1e-5f);
  ushort_t* yr = Y + (size_t)row * outStride;
#pragma unroll
  for (int i = 0; i < 5; i++) {
    int d = lane + 64 * i;
    yr[d] = f2b((v[i] - m) * inv * w[d] + b[d]);
  }
}

// ---------------- bf16 MFMA GEMM (R6 form: gload_lds, single buffer) ---------
// BM=MT*32, BK=64, BN=32*NT. 256 threads = 4 waves (2x2). Single LDS buffer,
// 2 __syncthreads/step. Swizzled K-contiguous layout (chunk j of row r at
// slot j^(r&7)): conflict-free (measured 0). Swapped MFMA -> D[n][m].
// T1 XCD remap (nbx % 8 == 0; bijective).
// Session ledger: tile shape (R1), XCD swizzle alone (R2), drain-0 dbuf (R3),
// raw-barrier counted-vmcnt (R4/R5: container hangs), occupancy MT=1 (R7),
// T14 reg-staging (R8: disaster), proj un-fuse (R9: -34us), ffn2 un-fuse
// (R10: -30us) -- all null or worse. R6 (both fusions, this form) = 994us
// best. R11: layer-4 dead-work elimination via `gath` row gather:
// after layer 4 only x[:,0] (CLS rows, global row 24*b) is consumed, so
// layer-4 proj/ffn1/ffn2 run at M=1024 on gathered/compact buffers (1/24
// the FLOPs, same per-row arithmetic -> bit-identical CLS results).
// `gath`: A row m reads global row m*gath; EPI=5 residual read uses the
// same multiplier while C/Cb write compact (gath=1 == R6 exactly).
// EPI: 1=bias+gelu->bf16, 2=bias+residual->f32, 3=bias+gelu->f32,
//      4=bias->bf16, 5=bias+residual->f32 C AND fused row-LN->bf16 Cb
//      (EPI=5 requires BN == N; NT=10, MT=2).
template <int EPI, int NT, int MT>
__global__ __launch_bounds__(256, 3) void gemm_mfma(
    const ushort_t* __restrict__ A, const ushort_t* __restrict__ W,
    const float* __restrict__ bias, const float* __restrict__ R,
    float* __restrict__ C, ushort_t* __restrict__ Cb,
    const float* __restrict__ lnw, const float* __restrict__ lnb,
    int M, int N, int K, int gath) {
  constexpr int BM_ = MT * 32, BK = 64;
  constexpr int BN = 32 * NT;
  constexpr int AR = BM_ / 32;   // A staging rounds (32 rows each)
  constexpr int WR = BN / 32;    // W staging rounds
  __shared__ __align__(16) ushort_t As[BM_ * BK];
  __shared__ __align__(16) ushort_t Ws[BN * BK];
  __shared__ float psum[2][(EPI == 5) ? BM_ : 4];  // fused-LN partials
  __shared__ float psq[2][(EPI == 5) ? BM_ : 4];

  int tid = threadIdx.x;
  int lane = tid & 63;
  int wv = tid >> 6;
  int wvM = wv & 1, wvN = wv >> 1;
  int laneM = lane & 15;
  int kgrp = lane >> 4;
  int sA = laneM & 7;

  // T1 XCD-aware remap (requires nbx % 8 == 0; bijective)
  int nbx = gridDim.x;
  int lid = blockIdx.x + nbx * blockIdx.y;
  int nchunk = nbx >> 3;
  int mb = (lid & 7) * nchunk + ((lid >> 3) % nchunk);
  int nb = (lid >> 3) / nchunk;
  int m0 = mb * BM_;
  int n0 = nb * BN;

  facc4 acc[MT][NT];
#pragma unroll
  for (int mt = 0; mt < MT; mt++)
#pragma unroll
    for (int nt = 0; nt < NT; nt++) acc[mt][nt] = (facc4){0.f, 0.f, 0.f, 0.f};

  int srow = tid >> 3;
  int jg = (tid & 7) ^ (srow & 7);
  const ushort_t* Ag = A + (size_t)(m0 + srow) * gath * K + jg * 8;
  const ushort_t* Wg = W + (size_t)(n0 + srow) * K + jg * 8;

  for (int k0 = 0; k0 < K; k0 += BK) {
#pragma unroll
    for (int r = 0; r < AR; r++)
      GLOAD_LDS16(Ag + (size_t)r * 32 * gath * K + k0, As + r * 2048 + tid * 8);
#pragma unroll
    for (int r = 0; r < WR; r++)
      GLOAD_LDS16(Wg + (size_t)r * 32 * K + k0, Ws + r * 2048 + tid * 8);
    __syncthreads();   // drains vmcnt (global_load_lds) + orders LDS use
#pragma unroll
    for (int kc = 0; kc < 2; kc++) {
      int jcol = ((kc * 4 + kgrp) ^ sA) * 8;
      bfrag8 af[MT];
#pragma unroll
      for (int mt = 0; mt < MT; mt++) {
        int row = wvM * (MT * 16) + mt * 16 + laneM;
        af[mt] = *(const bfrag8*)&As[row * 64 + jcol];
      }
#pragma unroll
      for (int nt = 0; nt < NT; nt++) {
        int nrow = wvN * (BN / 2) + nt * 16 + laneM;
        bfrag8 bf = *(const bfrag8*)&Ws[nrow * 64 + jcol];
#pragma unroll
        for (int mt = 0; mt < MT; mt++)
          acc[mt][nt] = __builtin_amdgcn_mfma_f32_16x16x32_bf16(
              bf, af[mt], acc[mt][nt], 0, 0, 0);   // swapped: D[n][m]
      }
    }
    __syncthreads();   // protect LDS from next iteration's staging
  }

  if constexpr (EPI == 5) {
    // ---- fused epilogue: v = acc + bias + R[m*gath]; C[m]=v; Cb[m]=LN(v) ----
    float rs[MT], rq[MT];
#pragma unroll
    for (int mt = 0; mt < MT; mt++) { rs[mt] = 0.f; rq[mt] = 0.f; }
#pragma unroll
    for (int mt = 0; mt < MT; mt++) {
      int m = m0 + wvM * (MT * 16) + mt * 16 + laneM;
#pragma unroll
      for (int nt = 0; nt < NT; nt++) {
        int n = n0 + wvN * (BN / 2) + nt * 16 + kgrp * 4;
        float4 bv = *(const float4*)(bias + n);
        size_t offR = (size_t)m * gath * N + n;
        float4 r = *(const float4*)(R + offR);
        facc4 a = acc[mt][nt];
        a[0] += bv.x + r.x; a[1] += bv.y + r.y;
        a[2] += bv.z + r.z; a[3] += bv.w + r.w;
        acc[mt][nt] = a;
        rs[mt] += a[0] + a[1] + a[2] + a[3];
        rq[mt] += a[0] * a[0] + a[1] * a[1] + a[2] * a[2] + a[3] * a[3];
      }
    }
    // reduce across the 4 kgrp lanes holding the same row (lanes ^16, ^32)
#pragma unroll
    for (int mt = 0; mt < MT; mt++) {
      rs[mt] += __shfl_xor(rs[mt], 16, 64);
      rs[mt] += __shfl_xor(rs[mt], 32, 64);
      rq[mt] += __shfl_xor(rq[mt], 16, 64);
      rq[mt] += __shfl_xor(rq[mt], 32, 64);
    }
    if (lane < 16) {   // kgrp == 0 lanes publish per-wvN row partials
#pragma unroll
      for (int mt = 0; mt < MT; mt++) {
        int lr = wvM * (MT * 16) + mt * 16 + laneM;
        psum[wvN][lr] = rs[mt];
        psq[wvN][lr] = rq[mt];
      }
    }
    __syncthreads();
#pragma unroll
    for (int mt = 0; mt < MT; mt++) {
      int lr = wvM * (MT * 16) + mt * 16 + laneM;
      int m = m0 + lr;
      float ts = psum[0][lr] + psum[1][lr];
      float tq = psq[0][lr] + psq[1][lr];
      float mean = ts * (1.0f / (float)D);
      float var = tq * (1.0f / (float)D) - mean * mean;
      float inv = 1.0f / sqrtf(var + 1e-5f);
#pragma unroll
      for (int nt = 0; nt < NT; nt++) {
        int n = n0 + wvN * (BN / 2) + nt * 16 + kgrp * 4;
        size_t off = (size_t)m * N + n;   // compact C/Cb
        facc4 a = acc[mt][nt];
        *(float4*)(C + off) = (float4){a[0], a[1], a[2], a[3]};
        float4 w4 = *(const float4*)(lnw + n);
        float4 b4 = *(const float4*)(lnb + n);
        ushort4 o;
        o.x = f2b((a[0] - mean) * inv * w4.x + b4.x);
        o.y = f2b((a[1] - mean) * inv * w4.y + b4.y);
        o.z = f2b((a[2] - mean) * inv * w4.z + b4.z);
        o.w = f2b((a[3] - mean) * inv * w4.w + b4.w);
        *(ushort4*)(Cb + off) = o;
      }
    }
  } else {
    // epilogue (transposed D): m = laneM-based, n = kgrp*4 + reg
#pragma unroll
    for (int mt = 0; mt < MT; mt++) {
      int m = m0 + wvM * (MT * 16) + mt * 16 + laneM;
#pragma unroll
      for (int nt = 0; nt < NT; nt++) {
        int n = n0 + wvN * (BN / 2) + nt * 16 + kgrp * 4;
        float4 bv = *(const float4*)(bias + n);
        facc4 a = acc[mt][nt];
        float v0 = a[0] + bv.x, v1 = a[1] + bv.y, v2 = a[2] + bv.z,
              v3 = a[3] + bv.w;
        size_t off = (size_t)m * N + n;
        if constexpr (EPI == 1) {
          ushort4 o;
          o.x = f2b(gelu_fast(v0)); o.y = f2b(gelu_fast(v1));
          o.z = f2b(gelu_fast(v2)); o.w = f2b(gelu_fast(v3));
          *(ushort4*)(Cb + off) = o;
        } else if constexpr (EPI == 2) {
          float4 r = *(const float4*)(R + off);
          float4 o = {v0 + r.x, v1 + r.y, v2 + r.z, v3 + r.w};
          *(float4*)(C + off) = o;
        } else if constexpr (EPI == 3) {
          float4 o = {gelu_fast(v0), gelu_fast(v1), gelu_fast(v2),
                      gelu_fast(v3)};
          *(float4*)(C + off) = o;
        } else {  // EPI == 4
          ushort4 o;
          o.x = f2b(v0); o.y = f2b(v1); o.z = f2b(v2); o.w = f2b(v3);
          *(ushort4*)(Cb + off) = o;
        }
      }
    }
  }
}

// ---------------- attention v2: one block per (b,h), conflict-free LDS -------
__global__ __launch_bounds__(256) void attn_kernel(
    const ushort_t* __restrict__ qkv, ushort_t* __restrict__ o) {
  int b = blockIdx.x >> 3;
  int h = blockIdx.x & 7;
  __shared__ __align__(16) float q[S][44];
  __shared__ __align__(16) float v[S][44];
  __shared__ __align__(16) float kT[DH][28];
  __shared__ __align__(16) float sc[S][28];
  int tid = threadIdx.x;
  const ushort_t* base = qkv + (size_t)b * S * (3 * D) + h * DH;

  for (int idx = tid; idx < 720; idx += 256) {
    int t = idx / 240;          // 0=q 1=k 2=v
    int r = idx % 240;
    int s = r / 10, dg = r % 10;
    ushort4 u = *(const ushort4*)(base + (size_t)s * (3 * D) + t * D + dg * 4);
    float4 f = {b2f(u.x), b2f(u.y), b2f(u.z), b2f(u.w)};
    if (t == 0) {
      *(float4*)&q[s][dg * 4] = f;
    } else if (t == 2) {
      *(float4*)&v[s][dg * 4] = f;
    } else {
      kT[dg * 4 + 0][s] = f.x;
      kT[dg * 4 + 1][s] = f.y;
      kT[dg * 4 + 2][s] = f.z;
      kT[dg * 4 + 3][s] = f.w;
    }
  }
  __syncthreads();

  if (tid < 144) {
    int i = tid / 6, jg = tid % 6;
    facc4 acc = {0.f, 0.f, 0.f, 0.f};
#pragma unroll
    for (int d = 0; d < DH; d++) {
      float qv = q[i][d];
      float4 kv = *(const float4*)&kT[d][jg * 4];
      acc[0] += qv * kv.x; acc[1] += qv * kv.y;
      acc[2] += qv * kv.z; acc[3] += qv * kv.w;
    }
    const float sca = 0.15811388300841897f;  // 1/sqrt(40)
    float4 ov = {acc[0] * sca, acc[1] * sca, acc[2] * sca, acc[3] * sca};
    *(float4*)&sc[i][jg * 4] = ov;
  }
  __syncthreads();

  if (tid < S) {
    float mx = -1e30f;
#pragma unroll
    for (int j = 0; j < S; j++) mx = fmaxf(mx, sc[tid][j]);
    float sum = 0.f;
#pragma unroll
    for (int j = 0; j < S; j++) {
      float e = __expf(sc[tid][j] - mx);
      sc[tid][j] = e;
      sum += e;
    }
    float rr = 1.0f / sum;
#pragma unroll
    for (int j = 0; j < S; j++) sc[tid][j] *= rr;
  }
  __syncthreads();

  if (tid < 240) {
    int i = tid / 10, dg = tid % 10;
    facc4 acc = {0.f, 0.f, 0.f, 0.f};
#pragma unroll
    for (int j = 0; j < S; j++) {
      float p = sc[i][j];
      float4 vv = *(const float4*)&v[j][dg * 4];
      acc[0] += p * vv.x; acc[1] += p * vv.y;
      acc[2] += p * vv.z; acc[3] += p * vv.w;
    }
    ushort4 ov;
    ov.x = f2b(acc[0]); ov.y = f2b(acc[1]);
    ov.z = f2b(acc[2]); ov.w = f2b(acc[3]);
    *(ushort4*)(o + (size_t)b * S * D + (size_t)i * D + h * DH + dg * 4) = ov;
  }
}

// ---------------- head tail: c = g@Wh2^T+bh2 ; cheb ; sigmoid ----------------
__global__ __launch_bounds__(256) void head_cheb(
    const float* __restrict__ g, const float* __restrict__ Wh2,
    const float* __restrict__ bh2, const float* __restrict__ k_norm,
    float* __restrict__ out) {
  int b = blockIdx.x;
  __shared__ float gs[D];
  __shared__ float cs[NM1];
  int tid = threadIdx.x;
  for (int i = tid; i < D; i += 256) gs[i] = g[(size_t)b * D + i];
  __syncthreads();
  if (tid < NM1) {
    const float* wr = Wh2 + (size_t)tid * D;
    float s = bh2[tid];
    for (int d = 0; d < D; d++) s += gs[d] * wr[d];
    cs[tid] = s;
  }
  __syncthreads();
  for (int t = tid; t < T_SZ; t += 256) {
    float xv = k_norm[(size_t)b * T_SZ + t];
    float tp = 1.f, tc = xv;
    float acc = cs[0] + cs[1] * xv;
#pragma unroll
    for (int n = 2; n < NM1; n++) {
      float tn = 2.f * xv * tc - tp;
      acc += cs[n] * tn;
      tp = tc;
      tc = tn;
    }
    out[(size_t)b * T_SZ + t] = 1.f / (1.f + expf(-acc));
  }
}

extern "C" void kernel_launch(void* const* d_in, const int* in_sizes, int n_in,
                              void* d_out, int out_size, void* d_ws,
                              size_t ws_size, hipStream_t stream) {
  const float* k_norm = (const float*)d_in[0];
  const float* ctx    = (const float*)d_in[1];
  const float* W_e    = (const float*)d_in[2];
  const float* b_e    = (const float*)d_in[3];
  const float* cls    = (const float*)d_in[4];
  const float* ln1_w  = (const float*)d_in[5];
  const float* ln1_b  = (const float*)d_in[6];
  const float* W_in   = (const float*)d_in[7];
  const float* b_in   = (const float*)d_in[8];
  const float* W_out  = (const float*)d_in[9];
  const float* b_out  = (const float*)d_in[10];
  const float* ln2_w  = (const float*)d_in[11];
  const float* ln2_b  = (const float*)d_in[12];
  const float* W1     = (const float*)d_in[13];
  const float* b1     = (const float*)d_in[14];
  const float* W2     = (const float*)d_in[15];
  const float* b2     = (const float*)d_in[16];
  const float* hln_w  = (const float*)d_in[17];
  const float* hln_b  = (const float*)d_in[18];
  const float* Wh1    = (const float*)d_in[19];
  const float* bh1    = (const float*)d_in[20];
  const float* Wh2    = (const float*)d_in[21];
  const float* bh2    = (const float*)d_in[22];
  float* out = (float*)d_out;

  float* x = (float*)d_ws;
  ushort_t* hbuf = (ushort_t*)(x + (size_t)M_ROWS * D);
  ushort_t* big = hbuf + (size_t)M_ROWS * D;
  ushort_t* wb_in = big + (size_t)M_ROWS * FF;
  ushort_t* wb_out = wb_in + (size_t)L_LAYERS * 3 * D * D;
  ushort_t* wb1 = wb_out + (size_t)L_LAYERS * D * D;
  ushort_t* wb2 = wb1 + (size_t)L_LAYERS * FF * D;
  ushort_t* wbh1 = wb2 + (size_t)L_LAYERS * D * FF;
  ushort_t* hcls = wbh1 + (size_t)D * D;
  float* ghead = (float*)(hcls + (size_t)B_SZ * D);
  // compact layer-4 CLS buffers (R11)
  float* xc = ghead + (size_t)B_SZ * D;                 // 1024 x 320 f32
  ushort_t* hbufc = (ushort_t*)(xc + (size_t)B_SZ * D); // 1024 x 320 bf16
  ushort_t* bigc = hbufc + (size_t)B_SZ * D;            // 1024 x 1280 bf16
  // attn output lives in the tail of big (cols 960..1280 region, disjoint
  // from the qkv output in cols 0..960; both dead once ffn1 overwrites big)
  ushort_t* abuf = big + (size_t)M_ROWS * 960;

  conv_all<<<6100, 256, 0, stream>>>(W_in, W_out, W1, W2, Wh1, wb_in);

  // embed + ln1(layer 0): writes x (f32) and hbuf = ln1_0(x) (bf16)
  embed_ln<<<M_ROWS / 4, 256, 0, stream>>>(ctx, W_e, b_e, cls, ln1_w, ln1_b,
                                           x, hbuf);

  for (int l = 0; l < L_LAYERS; l++) {
    gemm_mfma<4, 5, 4><<<dim3(M_ROWS / 128, (3 * D) / 160), 256, 0, stream>>>(
        hbuf, wb_in + (size_t)l * 3 * D * D, b_in + (size_t)l * 3 * D, nullptr,
        nullptr, big, nullptr, nullptr, M_ROWS, 3 * D, D, 1);
    attn_kernel<<<B_SZ * H, 256, 0, stream>>>(big, abuf);
    if (l + 1 < L_LAYERS) {
      // proj + residual + fused ln2 -> x (f32) and hbuf (bf16) [R6-proven]
      gemm_mfma<5, 10, 2><<<dim3(M_ROWS / 64, 1), 256, 0, stream>>>(
          abuf, wb_out + (size_t)l * D * D, b_out + (size_t)l * D, x, x, hbuf,
          ln2_w + (size_t)l * D, ln2_b + (size_t)l * D, M_ROWS, D, D, 1);
      gemm_mfma<1, 5, 4><<<dim3(M_ROWS / 128, FF / 160), 256, 0, stream>>>(
          hbuf, wb1 + (size_t)l * FF * D, b1 + (size_t)l * FF, nullptr,
          nullptr, big, nullptr, nullptr, M_ROWS, FF, D, 1);
      // ffn2 + residual + fused ln1(l+1) -> x (f32) and hbuf (bf16)
      gemm_mfma<5, 10, 2><<<dim3(M_ROWS / 64, 1), 256, 0, stream>>>(
          big, wb2 + (size_t)l * D * FF, b2 + (size_t)l * D, x, x, hbuf,
          ln1_w + (size_t)(l + 1) * D, ln1_b + (size_t)(l + 1) * D,
          M_ROWS, D, FF, 1);
    } else {
      // ---- layer 4: only CLS rows (global row 24*b) are ever consumed ----
      // gathered proj + residual + fused ln2 -> xc (f32) and hbufc (bf16)
      gemm_mfma<5, 10, 2><<<dim3(B_SZ / 64, 1), 256, 0, stream>>>(
          abuf, wb_out + (size_t)l * D * D, b_out + (size_t)l * D, x, xc,
          hbufc, ln2_w + (size_t)l * D, ln2_b + (size_t)l * D,
          B_SZ, D, D, S);
      // compact ffn1: M=1024
      gemm_mfma<1, 5, 4><<<dim3(B_SZ / 128, FF / 160), 256, 0, stream>>>(
          hbufc, wb1 + (size_t)l * FF * D, b1 + (size_t)l * FF, nullptr,
          nullptr, bigc, nullptr, nullptr, B_SZ, FF, D, 1);
      // compact ffn2 + residual -> xc
      gemm_mfma<2, 5, 2><<<dim3(B_SZ / 64, D / 160), 256, 0, stream>>>(
          bigc, wb2 + (size_t)l * D * FF, b2 + (size_t)l * D, xc, xc, nullptr,
          nullptr, nullptr, B_SZ, D, FF, 1);
    }
  }

  // head LN on compact CLS stream
  ln_kernel<<<B_SZ / 4, 256, 0, stream>>>(xc, hln_w, hln_b, hcls, D, D);
  gemm_mfma<3, 5, 2><<<dim3(B_SZ / 64, D / 160), 256, 0, stream>>>(
      hcls, wbh1, bh1, nullptr, ghead, nullptr, nullptr, nullptr,
      B_SZ, D, D, 1);
  head_cheb<<<B_SZ, 256, 0, stream>>>(ghead, Wh2, bh2, k_norm, out);
}